// Round 3
// baseline (184.875 us; speedup 1.0000x reference)
//
#include <hip/hip_runtime.h>
#include <hip/hip_bf16.h>
#include <cstddef>

#define FG 6
#define L 1024
#define NB 768
#define MN 8
#define H 16
#define HD 64
#define ADIM 1024
#define STAGES 4
#define SCALE 0.125f

typedef __attribute__((ext_vector_type(8))) short bf16x8;
typedef __attribute__((ext_vector_type(4))) float f32x4;
typedef __attribute__((address_space(3))) short lds_short_t;
typedef const __attribute__((address_space(1))) short g_short_t;

__device__ __forceinline__ int clampi(int v, int lo, int hi) {
  return v < lo ? lo : (v > hi ? hi : v);
}

__device__ __forceinline__ short f2bf(float f) {
  __hip_bfloat16 h = __float2bfloat16(f);
  return *reinterpret_cast<short*>(&h);
}

__device__ __forceinline__ void gload16(const short* g, short* l) {
  __builtin_amdgcn_global_load_lds((g_short_t*)g, (lds_short_t*)l, 16, 0, 0);
}

// fp32 -> bf16 bulk convert (8 elems/thread)
__global__ __launch_bounds__(256)
void conv_bf16(const float* __restrict__ in, short* __restrict__ out) {
  size_t i = ((size_t)blockIdx.x * 256 + threadIdx.x) * 8;
  float4 a = *(const float4*)(in + i);
  float4 b = *(const float4*)(in + i + 4);
  bf16x8 v;
  v[0] = f2bf(a.x); v[1] = f2bf(a.y); v[2] = f2bf(a.z); v[3] = f2bf(a.w);
  v[4] = f2bf(b.x); v[5] = f2bf(b.y); v[6] = f2bf(b.z); v[7] = f2bf(b.w);
  *(bf16x8*)(out + i) = v;
}

// in fp32 [K][N] -> out bf16 [N][K]  (B^T layout for the GEMM)
__global__ __launch_bounds__(256)
void transpose_conv(const float* __restrict__ in, short* __restrict__ out,
                    int K, int N) {
  __shared__ float tile[32][33];
  const int n0 = blockIdx.x * 32, k0 = blockIdx.y * 32;
  const int tx = threadIdx.x & 31, ty = threadIdx.x >> 5;
  #pragma unroll
  for (int i = 0; i < 4; ++i)
    tile[ty + i * 8][tx] = in[(size_t)(k0 + ty + i * 8) * N + n0 + tx];
  __syncthreads();
  #pragma unroll
  for (int i = 0; i < 4; ++i)
    out[(size_t)(n0 + ty + i * 8) * K + k0 + tx] =
        f2bf(tile[tx][ty + i * 8]);
}

// ===================== 128x128 m97-structure GEMM (proven) ================
// MODE 0: Q   A=xb gathered (bfid,btid), B=qwT[0:1024),    C=qbuf fp32 ldc1024
// MODE 2: OUT A=obuf direct,             B=owT,            C=d_out fp32 scatter
template<int MODE>
__global__ __launch_bounds__(256)
void mfma_gemm(const short* __restrict__ A, const short* __restrict__ B,
               void* __restrict__ Cv,
               const int* __restrict__ f_ids, const int* __restrict__ t_ids,
               const float* __restrict__ bias)
{
  constexpr int KT    = 16;                    // 1024 / 64
  constexpr int BCOL0 = (MODE == 1) ? 1024 : 0;

  __shared__ __align__(16) short As[8192];     // 128 rows x 64 bf16 (swizzled)
  __shared__ __align__(16) short Bs[8192];

  const int tid  = threadIdx.x;
  const int w    = tid >> 6, lane = tid & 63;
  const int row0 = blockIdx.y * 128, col0 = blockIdx.x * 128;

  size_t aoff[4], boff[4];
  short *adst[4], *bdst[4];
  #pragma unroll
  for (int c = 0; c < 4; ++c) {
    const int d = (w * 4 + c) * 64 + lane;
    const int r = d >> 3;
    const int ssrc = (d & 7) ^ (r & 7);
    long gr;
    if (MODE == 2) {
      gr = row0 + r;
    } else {
      const int rr = row0 + r;
      int bi, idx;
      if (MODE == 0) { bi = rr >= NB;          idx = rr - bi * NB; }
      else           { bi = rr >= NB * MN;     idx = rr - bi * NB * MN; }
      const int f = clampi(f_ids[idx], 0, FG - 1);
      const int q = clampi(t_ids[idx], 0, L - 1);
      gr = (long)(bi * FG + f) * L + q;
    }
    aoff[c] = (size_t)gr * 1024 + ssrc * 8;
    boff[c] = (size_t)(BCOL0 + col0 + r) * 1024 + ssrc * 8;
    adst[c] = As + (w * 4 + c) * 512;
    bdst[c] = Bs + (w * 4 + c) * 512;
  }

  const int lr = lane & 15, lq = lane >> 4;
  const int wrow = (w >> 1) * 64, wcol = (w & 1) * 64;
  const int sA = lr & 7;
  const char* As8 = (const char*)As;
  const char* Bs8 = (const char*)Bs;
  const int abase = (wrow + lr) * 128;
  const int bbase = (wcol + lr) * 128;

  f32x4 acc[4][4];
  #pragma unroll
  for (int m = 0; m < 4; ++m)
    #pragma unroll
    for (int n = 0; n < 4; ++n) acc[m][n] = (f32x4){0.f, 0.f, 0.f, 0.f};

  for (int kt = 0; kt < KT; ++kt) {
    #pragma unroll
    for (int c = 0; c < 4; ++c) {
      gload16(A + aoff[c] + kt * 64, adst[c]);
      gload16(B + boff[c] + kt * 64, bdst[c]);
    }
    __syncthreads();
    #pragma unroll
    for (int kk = 0; kk < 2; ++kk) {
      const int so = ((kk * 4 + lq) ^ sA) << 4;
      bf16x8 av[4], bv[4];
      #pragma unroll
      for (int m = 0; m < 4; ++m)
        av[m] = *(const bf16x8*)(As8 + abase + m * 2048 + so);
      #pragma unroll
      for (int n = 0; n < 4; ++n)
        bv[n] = *(const bf16x8*)(Bs8 + bbase + n * 2048 + so);
      #pragma unroll
      for (int m = 0; m < 4; ++m)
        #pragma unroll
        for (int n = 0; n < 4; ++n)
          acc[m][n] = __builtin_amdgcn_mfma_f32_16x16x32_bf16(
              av[m], bv[n], acc[m][n], 0, 0, 0);
    }
    __syncthreads();
  }

  if (MODE == 0) {
    float* C = (float*)Cv;
    #pragma unroll
    for (int m = 0; m < 4; ++m)
      #pragma unroll
      for (int j = 0; j < 4; ++j) {
        const int r = row0 + wrow + m * 16 + lq * 4 + j;
        #pragma unroll
        for (int n = 0; n < 4; ++n)
          C[(size_t)r * 1024 + col0 + wcol + n * 16 + lr] = acc[m][n][j];
      }
  } else if (MODE == 1) {
    short* C = (short*)Cv;
    #pragma unroll
    for (int m = 0; m < 4; ++m)
      #pragma unroll
      for (int j = 0; j < 4; ++j) {
        const int r = row0 + wrow + m * 16 + lq * 4 + j;
        #pragma unroll
        for (int n = 0; n < 4; ++n)
          C[(size_t)r * 2048 + col0 + wcol + n * 16 + lr] = f2bf(acc[m][n][j]);
      }
  } else {
    float* C = (float*)Cv;
    float bb[4];
    #pragma unroll
    for (int n = 0; n < 4; ++n) bb[n] = bias[col0 + wcol + n * 16 + lr];
    #pragma unroll
    for (int m = 0; m < 4; ++m)
      #pragma unroll
      for (int j = 0; j < 4; ++j) {
        const int r  = row0 + wrow + m * 16 + lq * 4 + j;
        const int bi = r >= NB;
        const int nn = r - bi * NB;
        const int bf = f_ids[nn], bt = t_ids[nn];
        const int qf = clampi(bf, 0, FG - 1), qi = clampi(bt, 0, L - 1);
        const bool valid = (bf == qf) && (bt == qi);
        const size_t obase = ((size_t)(bi * FG + qf) * L + qi) * 1024;
        #pragma unroll
        for (int n = 0; n < 4; ++n) {
          const int col = col0 + wcol + n * 16 + lr;
          C[obase + col] = valid ? (acc[m][n][j] + bb[n]) : 0.f;
        }
      }
  }
}

// ===================== 256x256 8-phase counted-vmcnt KV-GEMM ==============
// M=12288 (gathered via nfid/ntid), N=2048 (qkv_w cols 1024..3071), K=1024.
// 8 waves (2M x 4N), wave tile 128x64 with 2-way interleaved M-frags.
// LDS: A [2buf][2 rowhalf][128][64] swz slot^=(row&7);
//      B [2buf][2 khalf ][256][32] swz slot^=(row&3).
// Staging runs ~1.75 tiles ahead; counted vmcnt (10/8), never 0 in main loop.

#define BAR()   do { __builtin_amdgcn_s_barrier(); __builtin_amdgcn_sched_barrier(0); } while (0)
#define LGKM0() do { asm volatile("s_waitcnt lgkmcnt(0)" ::: "memory"); __builtin_amdgcn_sched_barrier(0); } while (0)
#define VMC(N)  do { asm volatile("s_waitcnt vmcnt(" #N ")" ::: "memory"); __builtin_amdgcn_sched_barrier(0); } while (0)
#define PRIO1   __builtin_amdgcn_s_setprio(1)
#define PRIO0   __builtin_amdgcn_s_setprio(0)

#define LDA(D, FB, KK, BUF)                                                   \
  { _Pragma("unroll")                                                         \
    for (int f_ = 0; f_ < 4; ++f_) {                                          \
      const int row_ = (2 * ((FB) + f_) + wm) * 16 + lr;                      \
      D[f_] = *(const bf16x8*)(As8 + (BUF) * 32768 + ((FB) >= 4 ? 16384 : 0)  \
               + (row_ & 127) * 128 + ((((KK) * 4 + lq) ^ aswz) << 4));       \
    } }

#define LDB(D, KK, BUF)                                                       \
  { _Pragma("unroll")                                                         \
    for (int g_ = 0; g_ < 4; ++g_) {                                          \
      const int row_ = wn * 64 + g_ * 16 + lr;                                \
      D[g_] = *(const bf16x8*)(Bs8 + (BUF) * 32768 + (KK) * 16384             \
               + row_ * 64 + ((lq ^ bswz) << 4));                             \
    } }

#define MM(AV, BV, FB)                                                        \
  { _Pragma("unroll")                                                         \
    for (int f_ = 0; f_ < 4; ++f_)                                            \
      _Pragma("unroll")                                                       \
      for (int g_ = 0; g_ < 4; ++g_)                                          \
        acc[(FB) + f_][g_] = __builtin_amdgcn_mfma_f32_16x16x32_bf16(         \
            AV[f_], BV[g_], acc[(FB) + f_][g_], 0, 0, 0); }

__global__ __launch_bounds__(512, 2)
void kv_gemm8(const short* __restrict__ A, const short* __restrict__ B,
              short* __restrict__ C,
              const int* __restrict__ f_ids, const int* __restrict__ t_ids)
{
  __shared__ __align__(16) short As[32768];  // 64 KiB
  __shared__ __align__(16) short Bs[32768];  // 64 KiB

  const int tid = threadIdx.x;
  const int w = tid >> 6, lane = tid & 63;
  const int wm = w >> 2, wn = w & 3;
  const int lr = lane & 15, lq = lane >> 4;
  const int row0 = blockIdx.y * 256;
  const int col0 = blockIdx.x * 256;

  // ---- staging sources: A = 4 gathered rows, B = 4 weight rows ----
  int aoff[2][2];
  const int sA = ((lane & 7) ^ (lane >> 3)) * 8;
  #pragma unroll
  for (int h = 0; h < 2; ++h)
    #pragma unroll
    for (int c = 0; c < 2; ++c) {
      const int tr = h * 128 + w * 16 + c * 8 + (lane >> 3);
      const int rr = row0 + tr;
      const int bi = rr >= NB * MN;
      const int idx = rr - bi * (NB * MN);
      const int f = clampi(f_ids[idx], 0, FG - 1);
      const int q = clampi(t_ids[idx], 0, L - 1);
      aoff[h][c] = ((bi * FG + f) * L + q) * 1024 + sA;
    }
  int boff[2][2];
  const int sB = ((lane & 3) ^ ((lane >> 2) & 3)) * 8;
  #pragma unroll
  for (int h = 0; h < 2; ++h)
    #pragma unroll
    for (int c = 0; c < 2; ++c) {
      const int br = w * 32 + c * 16 + (lane >> 2);
      boff[h][c] = (1024 + col0 + br) * 1024 + h * 32 + sB;
    }

  auto stgA = [&](int h, int kt, int buf) {
    gload16(A + aoff[h][0] + kt * 64, As + buf * 16384 + h * 8192 + (w * 2 + 0) * 512);
    gload16(A + aoff[h][1] + kt * 64, As + buf * 16384 + h * 8192 + (w * 2 + 1) * 512);
  };
  auto stgB = [&](int h, int kt, int buf) {
    gload16(B + boff[h][0] + kt * 64, Bs + buf * 16384 + h * 8192 + (w * 2 + 0) * 512);
    gload16(B + boff[h][1] + kt * 64, Bs + buf * 16384 + h * 8192 + (w * 2 + 1) * 512);
  };

  const char* As8 = (const char*)As;
  const char* Bs8 = (const char*)Bs;
  const int aswz = lr & 7;
  const int bswz = lr & 3;

  f32x4 acc[8][4];
  #pragma unroll
  for (int f = 0; f < 8; ++f)
    #pragma unroll
    for (int g = 0; g < 4; ++g) acc[f][g] = (f32x4){0.f, 0.f, 0.f, 0.f};

  bf16x8 av[4], bv0[4], bv1[4];

  // ---- prologue: Bk0(0),Bk1(0),A0(0),A1(0),Bk0(1),Bk1(1),A0(1) ----
  stgB(0, 0, 0); stgB(1, 0, 0); stgA(0, 0, 0); stgA(1, 0, 0);
  stgB(0, 1, 1); stgB(1, 1, 1); stgA(0, 1, 1);
  VMC(8); BAR();

  // ---- main loop: iterations compute tiles (2I, 2I+1) ----
  for (int I = 0; I < 7; ++I) {
    const int t1 = 2 * I + 1, t2 = 2 * I + 2, t3 = 2 * I + 3;
    // p1: tile even, f0-3 x kk0
    LDA(av, 0, 0, 0); LDB(bv0, 0, 0);
    stgA(1, t1, 1);
    BAR(); LGKM0();
    PRIO1; MM(av, bv0, 0); PRIO0;
    BAR();
    // p2: f0-3 x kk1
    LDA(av, 0, 1, 0); LDB(bv1, 1, 0);
    stgB(0, t2, 0);
    BAR(); LGKM0();
    PRIO1; MM(av, bv1, 0); PRIO0;
    VMC(10); BAR();
    // p3: f4-7 x kk0
    LDA(av, 4, 0, 0);
    stgB(1, t2, 0);
    BAR(); LGKM0();
    PRIO1; MM(av, bv0, 4); PRIO0;
    BAR();
    // p4: f4-7 x kk1
    LDA(av, 4, 1, 0);
    stgA(0, t2, 0);
    BAR(); LGKM0();
    PRIO1; MM(av, bv1, 4); PRIO0;
    VMC(8); BAR();
    // p5: tile odd, f0-3 x kk0
    LDA(av, 0, 0, 1); LDB(bv0, 0, 1);
    stgA(1, t2, 0);
    BAR(); LGKM0();
    PRIO1; MM(av, bv0, 0); PRIO0;
    BAR();
    // p6: f0-3 x kk1
    LDA(av, 0, 1, 1); LDB(bv1, 1, 1);
    stgB(0, t3, 1);
    BAR(); LGKM0();
    PRIO1; MM(av, bv1, 0); PRIO0;
    VMC(10); BAR();
    // p7: f4-7 x kk0
    LDA(av, 4, 0, 1);
    stgB(1, t3, 1);
    BAR(); LGKM0();
    PRIO1; MM(av, bv0, 4); PRIO0;
    BAR();
    // p8: f4-7 x kk1
    LDA(av, 4, 1, 1);
    stgA(0, t3, 1);
    BAR(); LGKM0();
    PRIO1; MM(av, bv1, 4); PRIO0;
    VMC(8); BAR();
  }

  // ---- peeled final iteration: tiles 14 (buf0), 15 (buf1) ----
  {
    // p1
    LDA(av, 0, 0, 0); LDB(bv0, 0, 0);
    stgA(1, 15, 1);
    BAR(); LGKM0();
    PRIO1; MM(av, bv0, 0); PRIO0;
    BAR();
    // p2
    LDA(av, 0, 1, 0); LDB(bv1, 1, 0);
    BAR(); LGKM0();
    PRIO1; MM(av, bv1, 0); PRIO0;
    VMC(8); BAR();
    // p3
    LDA(av, 4, 0, 0);
    BAR(); LGKM0();
    PRIO1; MM(av, bv0, 4); PRIO0;
    BAR();
    // p4
    LDA(av, 4, 1, 0);
    BAR(); LGKM0();
    PRIO1; MM(av, bv1, 4); PRIO0;
    VMC(2); BAR();
    // p5
    LDA(av, 0, 0, 1); LDB(bv0, 0, 1);
    BAR(); LGKM0();
    PRIO1; MM(av, bv0, 0); PRIO0;
    BAR();
    // p6
    LDA(av, 0, 1, 1); LDB(bv1, 1, 1);
    BAR(); LGKM0();
    PRIO1; MM(av, bv1, 0); PRIO0;
    VMC(0); BAR();
    // p7
    LDA(av, 4, 0, 1);
    BAR(); LGKM0();
    PRIO1; MM(av, bv0, 4); PRIO0;
    BAR();
    // p8
    LDA(av, 4, 1, 1);
    LGKM0();
    PRIO1; MM(av, bv1, 4); PRIO0;
  }

  // ---- epilogue: bf16 C, ldc 2048 ----
  #pragma unroll
  for (int f = 0; f < 8; ++f) {
    #pragma unroll
    for (int j = 0; j < 4; ++j) {
      const int r = row0 + (2 * f + wm) * 16 + lq * 4 + j;
      short* cp = C + (size_t)r * 2048 + col0 + wn * 64 + lr;
      #pragma unroll
      for (int g = 0; g < 4; ++g)
        cp[g * 16] = f2bf(acc[f][g][j]);
    }
  }
}

// One wave per (bi, n, h). Fuses q/k/v ray rotation, scores, softmax, PV,
// inverse rotation. q fp32 in, kv bf16 in, out bf16 (feeds OUT-GEMM).
__global__ __launch_bounds__(256)
void attn_kernel(const float* __restrict__ dray,
                 const int* __restrict__ bfid, const int* __restrict__ blid,
                 const int* __restrict__ bsid,
                 const int* __restrict__ nfid, const int* __restrict__ ntid,
                 const int* __restrict__ nlid, const int* __restrict__ nsid,
                 const int* __restrict__ nmask,
                 const float* __restrict__ qbuf,
                 const __hip_bfloat16* __restrict__ kvbuf,
                 __hip_bfloat16* __restrict__ obuf)
{
  const int lane = threadIdx.x & 63;
  const int gw   = blockIdx.x * 4 + (threadIdx.x >> 6);
  const int h    = gw & (H - 1);
  const int bn   = gw >> 4;
  const int n    = bn % NB;

  int st = clampi(bsid[n], 0, STAGES - 1);
  int f  = clampi(bfid[n], 0, FG - 1);
  int lc = clampi(blid[n], 0, L - 1);
  const float* dqp = dray + ((size_t)(st * FG + f) * L + lc) * 9;
  float dq[9];
  #pragma unroll
  for (int t = 0; t < 9; ++t) dq[t] = dqp[t];

  const float qraw = qbuf[(size_t)bn * ADIM + h * HD + lane];
  const int rr = lane & 15;

  float x0 = __shfl(qraw, rr), x1 = __shfl(qraw, 16 + rr), x2 = __shfl(qraw, 32 + rr);
  float q0 = dq[0]*x0 + dq[1]*x1 + dq[2]*x2;
  float q1 = dq[3]*x0 + dq[4]*x1 + dq[5]*x2;
  float q2 = dq[6]*x0 + dq[7]*x1 + dq[8]*x2;
  float qd = lane < 16 ? q0 : lane < 32 ? q1 : lane < 48 ? q2 : qraw;

  const __hip_bfloat16* kvb = kvbuf + (size_t)bn * MN * 2048 + h * HD;
  float s[MN], vd[MN];
  #pragma unroll
  for (int m = 0; m < MN; ++m) {
    const int idx = n * MN + m;
    int nst = clampi(nsid[idx], 0, STAGES - 1);
    int nfc = clampi(nfid[idx], 0, FG - 1);
    int nlc = clampi(nlid[idx], 0, L - 1);
    const float* dkp = dray + ((size_t)(nst * FG + nfc) * L + nlc) * 9;
    float dk[9];
    #pragma unroll
    for (int t = 0; t < 9; ++t) dk[t] = dkp[t];

    float kraw = __bfloat162float(kvb[(size_t)m * 2048 + lane]);
    float k0 = __shfl(kraw, rr), k1 = __shfl(kraw, 16 + rr), k2 = __shfl(kraw, 32 + rr);
    float kr0 = dk[0]*k0 + dk[1]*k1 + dk[2]*k2;
    float kr1 = dk[3]*k0 + dk[4]*k1 + dk[5]*k2;
    float kr2 = dk[6]*k0 + dk[7]*k1 + dk[8]*k2;
    float kd = lane < 16 ? kr0 : lane < 32 ? kr1 : lane < 48 ? kr2 : kraw;

    float p = qd * kd;
    #pragma unroll
    for (int off = 32; off; off >>= 1) p += __shfl_xor(p, off);
    s[m] = p;

    float vraw = __bfloat162float(kvb[(size_t)m * 2048 + 1024 + lane]);
    float v0 = __shfl(vraw, rr), v1 = __shfl(vraw, 16 + rr), v2 = __shfl(vraw, 32 + rr);
    float vr0 = dk[0]*v0 + dk[1]*v1 + dk[2]*v2;
    float vr1 = dk[3]*v0 + dk[4]*v1 + dk[5]*v2;
    float vr2 = dk[6]*v0 + dk[7]*v1 + dk[8]*v2;
    vd[m] = lane < 16 ? vr0 : lane < 32 ? vr1 : lane < 48 ? vr2 : vraw;
  }

  float mx = -INFINITY;
  #pragma unroll
  for (int m = 0; m < MN; ++m) {
    const int idx = n * MN + m;
    int nf = nfid[idx], nt = ntid[idx];
    bool ok = (nmask[idx] != 0) && nf >= 0 && nf < FG && nt >= 0 && nt < L;
    s[m] = ok ? s[m] * SCALE : -INFINITY;
    mx = fmaxf(mx, s[m]);
  }
  float den = 0.f;
  #pragma unroll
  for (int m = 0; m < MN; ++m) { s[m] = expf(s[m] - mx); den += s[m]; }
  float inv = 1.0f / den;

  float od = 0.f;
  #pragma unroll
  for (int m = 0; m < MN; ++m) od += s[m] * vd[m];
  od *= inv;

  float y0 = __shfl(od, rr), y1 = __shfl(od, 16 + rr), y2 = __shfl(od, 32 + rr);
  float t0 = dq[0]*y0 + dq[3]*y1 + dq[6]*y2;
  float t1 = dq[1]*y0 + dq[4]*y1 + dq[7]*y2;
  float t2 = dq[2]*y0 + dq[5]*y1 + dq[8]*y2;
  float outd = lane < 16 ? t0 : lane < 32 ? t1 : lane < 48 ? t2 : od;

  obuf[(size_t)bn * ADIM + h * HD + lane] = __float2bfloat16(outd);
}

extern "C" void kernel_launch(void* const* d_in, const int* in_sizes, int n_in,
                              void* d_out, int out_size, void* d_ws, size_t ws_size,
                              hipStream_t stream) {
  const float* x     = (const float*)d_in[0];
  const float* qkv_w = (const float*)d_in[1];
  const float* out_w = (const float*)d_in[2];
  const float* out_b = (const float*)d_in[3];
  const float* dray  = (const float*)d_in[4];
  const int* bfid  = (const int*)d_in[5];
  const int* btid  = (const int*)d_in[6];
  const int* blid  = (const int*)d_in[7];
  const int* bsid  = (const int*)d_in[8];
  const int* nfid  = (const int*)d_in[9];
  const int* ntid  = (const int*)d_in[10];
  const int* nlid  = (const int*)d_in[11];
  const int* nsid  = (const int*)d_in[12];
  const int* nmask = (const int*)d_in[13];

  char* ws = (char*)d_ws;
  short* xb    = (short*)(ws);                  // 12288*1024 bf16 = 25165824 B
  short* qwT   = (short*)(ws + 25165824);       // 3072*1024  bf16 =  6291456 B
  short* owT   = (short*)(ws + 31457280);       // 1024*1024  bf16 =  2097152 B
  float* qbuf  = (float*)(ws + 33554432);       // 1536*1024  f32  =  6291456 B
  short* kvbuf = (short*)(ws + 39845888);       // 12288*2048 bf16 = 50331648 B
  short* obuf  = (short*)(ws + 90177536);       // 1536*1024  bf16 =  3145728 B

  hipMemsetAsync(d_out, 0, (size_t)out_size * sizeof(float), stream);

  conv_bf16<<<6144, 256, 0, stream>>>(x, xb);
  transpose_conv<<<dim3(96, 32), 256, 0, stream>>>(qkv_w, qwT, 1024, 3072);
  transpose_conv<<<dim3(32, 32), 256, 0, stream>>>(out_w, owT, 1024, 1024);

  // Q projection: 1536 x 1024 x 1024 (m97 structure)
  mfma_gemm<0><<<dim3(8, 12), 256, 0, stream>>>(xb, qwT, qbuf, bfid, btid, nullptr);
  // KV projection: 12288 x 2048 x 1024 (256^2 8-phase)
  kv_gemm8<<<dim3(8, 48), 512, 0, stream>>>(xb, qwT, kvbuf, nfid, ntid);
  // fused rotations + attention
  attn_kernel<<<6144, 256, 0, stream>>>(dray, bfid, blid, bsid,
                                        nfid, ntid, nlid, nsid, nmask,
                                        qbuf, (const __hip_bfloat16*)kvbuf,
                                        (__hip_bfloat16*)obuf);
  // output projection + bias + valid mask + scatter: 1536 x 1024 x 1024
  mfma_gemm<2><<<dim3(8, 12), 256, 0, stream>>>(obuf, owT, d_out, bfid, btid, out_b);
}

// Round 4
// 181.034 us; speedup vs baseline: 1.0212x; 1.0212x over previous
//
#include <hip/hip_runtime.h>
#include <hip/hip_bf16.h>
#include <cstddef>

#define FG 6
#define L 1024
#define NB 768
#define MN 8
#define H 16
#define HD 64
#define ADIM 1024
#define STAGES 4
#define SCALE 0.125f

typedef __attribute__((ext_vector_type(8))) short bf16x8;
typedef __attribute__((ext_vector_type(4))) float f32x4;
typedef __attribute__((address_space(3))) short lds_short_t;
typedef const __attribute__((address_space(1))) short g_short_t;

__device__ __forceinline__ int clampi(int v, int lo, int hi) {
  return v < lo ? lo : (v > hi ? hi : v);
}

__device__ __forceinline__ short f2bf(float f) {
  __hip_bfloat16 h = __float2bfloat16(f);
  return *reinterpret_cast<short*>(&h);
}

__device__ __forceinline__ void gload16(const short* g, short* l) {
  __builtin_amdgcn_global_load_lds((g_short_t*)g, (lds_short_t*)l, 16, 0, 0);
}

// fp32 -> bf16 bulk convert (8 elems/thread)
__global__ __launch_bounds__(256)
void conv_bf16(const float* __restrict__ in, short* __restrict__ out) {
  size_t i = ((size_t)blockIdx.x * 256 + threadIdx.x) * 8;
  float4 a = *(const float4*)(in + i);
  float4 b = *(const float4*)(in + i + 4);
  bf16x8 v;
  v[0] = f2bf(a.x); v[1] = f2bf(a.y); v[2] = f2bf(a.z); v[3] = f2bf(a.w);
  v[4] = f2bf(b.x); v[5] = f2bf(b.y); v[6] = f2bf(b.z); v[7] = f2bf(b.w);
  *(bf16x8*)(out + i) = v;
}

// in fp32 [K][N] -> out bf16 [N][K]  (B^T layout for the GEMM)
__global__ __launch_bounds__(256)
void transpose_conv(const float* __restrict__ in, short* __restrict__ out,
                    int K, int N) {
  __shared__ float tile[32][33];
  const int n0 = blockIdx.x * 32, k0 = blockIdx.y * 32;
  const int tx = threadIdx.x & 31, ty = threadIdx.x >> 5;
  #pragma unroll
  for (int i = 0; i < 4; ++i)
    tile[ty + i * 8][tx] = in[(size_t)(k0 + ty + i * 8) * N + n0 + tx];
  __syncthreads();
  #pragma unroll
  for (int i = 0; i < 4; ++i)
    out[(size_t)(n0 + ty + i * 8) * K + k0 + tx] =
        f2bf(tile[tx][ty + i * 8]);
}

// ===================== 128x128 m97-structure GEMM (proven) ================
// MODE 0: Q   A=xb gathered (bfid,btid), B=qwT[0:1024),    C=qbuf fp32 ldc1024
// MODE 2: OUT A=obuf direct,             B=owT,            C=d_out fp32 scatter
template<int MODE>
__global__ __launch_bounds__(256)
void mfma_gemm(const short* __restrict__ A, const short* __restrict__ B,
               void* __restrict__ Cv,
               const int* __restrict__ f_ids, const int* __restrict__ t_ids,
               const float* __restrict__ bias)
{
  constexpr int KT    = 16;                    // 1024 / 64
  constexpr int BCOL0 = (MODE == 1) ? 1024 : 0;

  __shared__ __align__(16) short As[8192];     // 128 rows x 64 bf16 (swizzled)
  __shared__ __align__(16) short Bs[8192];

  const int tid  = threadIdx.x;
  const int w    = tid >> 6, lane = tid & 63;
  const int row0 = blockIdx.y * 128, col0 = blockIdx.x * 128;

  size_t aoff[4], boff[4];
  short *adst[4], *bdst[4];
  #pragma unroll
  for (int c = 0; c < 4; ++c) {
    const int d = (w * 4 + c) * 64 + lane;
    const int r = d >> 3;
    const int ssrc = (d & 7) ^ (r & 7);
    long gr;
    if (MODE == 2) {
      gr = row0 + r;
    } else {
      const int rr = row0 + r;
      int bi, idx;
      if (MODE == 0) { bi = rr >= NB;          idx = rr - bi * NB; }
      else           { bi = rr >= NB * MN;     idx = rr - bi * NB * MN; }
      const int f = clampi(f_ids[idx], 0, FG - 1);
      const int q = clampi(t_ids[idx], 0, L - 1);
      gr = (long)(bi * FG + f) * L + q;
    }
    aoff[c] = (size_t)gr * 1024 + ssrc * 8;
    boff[c] = (size_t)(BCOL0 + col0 + r) * 1024 + ssrc * 8;
    adst[c] = As + (w * 4 + c) * 512;
    bdst[c] = Bs + (w * 4 + c) * 512;
  }

  const int lr = lane & 15, lq = lane >> 4;
  const int wrow = (w >> 1) * 64, wcol = (w & 1) * 64;
  const int sA = lr & 7;
  const char* As8 = (const char*)As;
  const char* Bs8 = (const char*)Bs;
  const int abase = (wrow + lr) * 128;
  const int bbase = (wcol + lr) * 128;

  f32x4 acc[4][4];
  #pragma unroll
  for (int m = 0; m < 4; ++m)
    #pragma unroll
    for (int n = 0; n < 4; ++n) acc[m][n] = (f32x4){0.f, 0.f, 0.f, 0.f};

  for (int kt = 0; kt < KT; ++kt) {
    #pragma unroll
    for (int c = 0; c < 4; ++c) {
      gload16(A + aoff[c] + kt * 64, adst[c]);
      gload16(B + boff[c] + kt * 64, bdst[c]);
    }
    __syncthreads();
    #pragma unroll
    for (int kk = 0; kk < 2; ++kk) {
      const int so = ((kk * 4 + lq) ^ sA) << 4;
      bf16x8 av[4], bv[4];
      #pragma unroll
      for (int m = 0; m < 4; ++m)
        av[m] = *(const bf16x8*)(As8 + abase + m * 2048 + so);
      #pragma unroll
      for (int n = 0; n < 4; ++n)
        bv[n] = *(const bf16x8*)(Bs8 + bbase + n * 2048 + so);
      #pragma unroll
      for (int m = 0; m < 4; ++m)
        #pragma unroll
        for (int n = 0; n < 4; ++n)
          acc[m][n] = __builtin_amdgcn_mfma_f32_16x16x32_bf16(
              av[m], bv[n], acc[m][n], 0, 0, 0);
    }
    __syncthreads();
  }

  if (MODE == 0) {
    float* C = (float*)Cv;
    #pragma unroll
    for (int m = 0; m < 4; ++m)
      #pragma unroll
      for (int j = 0; j < 4; ++j) {
        const int r = row0 + wrow + m * 16 + lq * 4 + j;
        #pragma unroll
        for (int n = 0; n < 4; ++n)
          C[(size_t)r * 1024 + col0 + wcol + n * 16 + lr] = acc[m][n][j];
      }
  } else {
    float* C = (float*)Cv;
    float bb[4];
    #pragma unroll
    for (int n = 0; n < 4; ++n) bb[n] = bias[col0 + wcol + n * 16 + lr];
    #pragma unroll
    for (int m = 0; m < 4; ++m)
      #pragma unroll
      for (int j = 0; j < 4; ++j) {
        const int r  = row0 + wrow + m * 16 + lq * 4 + j;
        const int bi = r >= NB;
        const int nn = r - bi * NB;
        const int bf = f_ids[nn], bt = t_ids[nn];
        const int qf = clampi(bf, 0, FG - 1), qi = clampi(bt, 0, L - 1);
        const bool valid = (bf == qf) && (bt == qi);
        const size_t obase = ((size_t)(bi * FG + qf) * L + qi) * 1024;
        #pragma unroll
        for (int n = 0; n < 4; ++n) {
          const int col = col0 + wcol + n * 16 + lr;
          C[obase + col] = valid ? (acc[m][n][j] + bb[n]) : 0.f;
        }
      }
  }
}

// ============ 192x256 read-ahead counted-lgkm KV-GEMM =====================
// M=12288 gathered, N=2048 (qkv_w cols 1024..3071), K=1024. Grid 8x64 = 512
// blocks = exactly 2 rounds on 256 CUs. 8 waves (2M x 4N), wave tile 96x64
// (6 M-frags). One barrier per phase; ds_reads for cluster p+1 issued BEFORE
// cluster p's MFMA, waited with counted lgkmcnt -> LDS drain overlaps MFMA.
// vmcnt(2) only at p3/p7, one phase before the staged data's first read so a
// barrier separates every wave's vmcnt from every wave's dependent ds_read.
// LDS: A [2buf][192][64], B [2buf][256][64], both slot ^= (row&7): conflict-
// free (2-way lr/lr+8 aliasing = free).

#define BAR()   do { __builtin_amdgcn_s_barrier(); __builtin_amdgcn_sched_barrier(0); } while (0)
#define LGKM(N) do { asm volatile("s_waitcnt lgkmcnt(" #N ")" ::: "memory"); __builtin_amdgcn_sched_barrier(0); } while (0)
#define VMC(N)  do { asm volatile("s_waitcnt vmcnt(" #N ")" ::: "memory"); __builtin_amdgcn_sched_barrier(0); } while (0)
#define PRIO1   __builtin_amdgcn_s_setprio(1)
#define PRIO0   __builtin_amdgcn_s_setprio(0)

#define LDA6(D, FB, KK, BUF)                                                  \
  { _Pragma("unroll")                                                         \
    for (int f_ = 0; f_ < 3; ++f_) {                                          \
      const int row_ = (2 * ((FB) + f_) + wm) * 16 + lr;                      \
      D[f_] = *(const bf16x8*)(As8 + (BUF) * 24576 + row_ * 128               \
               + ((((KK) * 4 + lq) ^ swz) << 4));                             \
    } }

#define LDB4(D, KK, BUF)                                                      \
  { _Pragma("unroll")                                                         \
    for (int g_ = 0; g_ < 4; ++g_) {                                          \
      const int row_ = wn * 64 + g_ * 16 + lr;                                \
      D[g_] = *(const bf16x8*)(Bs8 + (BUF) * 32768 + row_ * 128               \
               + ((((KK) * 4 + lq) ^ swz) << 4));                             \
    } }

#define MM6(AV, BV, FB)                                                       \
  { _Pragma("unroll")                                                         \
    for (int f_ = 0; f_ < 3; ++f_)                                            \
      _Pragma("unroll")                                                       \
      for (int g_ = 0; g_ < 4; ++g_)                                          \
        acc[(FB) + f_][g_] = __builtin_amdgcn_mfma_f32_16x16x32_bf16(         \
            AV[f_], BV[g_], acc[(FB) + f_][g_], 0, 0, 0); }

__global__ __launch_bounds__(512, 2)
void kv_gemm192(const short* __restrict__ A, const short* __restrict__ B,
                short* __restrict__ C,
                const int* __restrict__ f_ids, const int* __restrict__ t_ids)
{
  __shared__ __align__(16) short As[24576];   // 2 x 192 x 64 = 48 KiB
  __shared__ __align__(16) short Bs[32768];   // 2 x 256 x 64 = 64 KiB

  const int tid = threadIdx.x;
  const int w = tid >> 6, lane = tid & 63;
  const int wm = w >> 2, wn = w & 3;
  const int lr = lane & 15, lq = lane >> 4;
  const int row0 = blockIdx.y * 192;
  const int col0 = blockIdx.x * 256;

  // inverse-swizzled source offset (elements); same for A chunks & B halves
  const int ssrc = (((tid & 7) ^ ((tid >> 3) & 7))) * 8;

  size_t a_src[3];
  #pragma unroll
  for (int c = 0; c < 3; ++c) {
    const int rr = row0 + c * 64 + (tid >> 3);
    const int bi = rr >= NB * MN;
    const int idx = rr - bi * (NB * MN);
    const int f = clampi(f_ids[idx], 0, FG - 1);
    const int q = clampi(t_ids[idx], 0, L - 1);
    a_src[c] = (size_t)((bi * FG + f) * L + q) * 1024 + ssrc;
  }
  size_t b_src[2][2];
  #pragma unroll
  for (int h = 0; h < 2; ++h)
    #pragma unroll
    for (int i = 0; i < 2; ++i)
      b_src[h][i] = (size_t)(1024 + col0 + h * 128 + ((tid + i * 512) >> 3)) * 1024 + ssrc;

  auto stgA = [&](int c, int kt, int buf) {
    gload16(A + a_src[c] + kt * 64, As + buf * 12288 + c * 4096 + tid * 8);
  };
  auto stgB = [&](int h, int kt, int buf) {
    gload16(B + b_src[h][0] + kt * 64, Bs + buf * 16384 + h * 8192 + tid * 8);
    gload16(B + b_src[h][1] + kt * 64, Bs + buf * 16384 + h * 8192 + 4096 + tid * 8);
  };

  const char* As8 = (const char*)As;
  const char* Bs8 = (const char*)Bs;
  const int swz = lane & 7;

  f32x4 acc[6][4];
  #pragma unroll
  for (int f = 0; f < 6; ++f)
    #pragma unroll
    for (int g = 0; g < 4; ++g) acc[f][g] = (f32x4){0.f, 0.f, 0.f, 0.f};

  bf16x8 avA[3], avB[3], bv0[4], bv1[4];

  // prologue: t0 full (7 ops) + t1 B,Ac0 (5 ops); wait t0; pre-issue c(p1)
  stgB(0, 0, 0); stgB(1, 0, 0); stgA(0, 0, 0); stgA(1, 0, 0); stgA(2, 0, 0);
  stgB(0, 1, 1); stgB(1, 1, 1); stgA(0, 1, 1);
  VMC(5); BAR();
  LDA6(avA, 0, 0, 0); LDB4(bv0, 0, 0);

  for (int I = 0; I < 7; ++I) {
    const int kA = 2 * I + 1, kB = 2 * I + 2, kC = 2 * I + 3;
    // p1: MFMA(FB0,kk0,b0); readahead FB0/kk1/b0 + B kk1 b0
    BAR(); stgA(1, kA, 1);
    LDA6(avB, 0, 1, 0); LDB4(bv1, 1, 0);
    LGKM(7); PRIO1; MM6(avA, bv0, 0); PRIO0;
    // p2
    BAR(); stgA(2, kA, 1);
    LDA6(avA, 3, 0, 0);
    LGKM(3); PRIO1; MM6(avB, bv1, 0); PRIO0;
    // p3 (vmcnt for b1 tile, one phase before its first read-issue)
    BAR(); stgB(0, kB, 0); VMC(2);
    LDA6(avB, 3, 1, 0);
    LGKM(3); PRIO1; MM6(avA, bv0, 3); PRIO0;
    // p4: readahead switches to b1
    BAR(); stgB(1, kB, 0); stgA(0, kB, 0);
    LDA6(avA, 0, 0, 1); LDB4(bv0, 0, 1);
    LGKM(7); PRIO1; MM6(avB, bv1, 3); PRIO0;
    // p5
    BAR(); stgA(1, kB, 0);
    LDA6(avB, 0, 1, 1); LDB4(bv1, 1, 1);
    LGKM(7); PRIO1; MM6(avA, bv0, 0); PRIO0;
    // p6
    BAR(); stgA(2, kB, 0);
    LDA6(avA, 3, 0, 1);
    LGKM(3); PRIO1; MM6(avB, bv1, 0); PRIO0;
    // p7 (vmcnt for next b0 tile)
    BAR(); stgB(0, kC, 1); VMC(2);
    LDA6(avB, 3, 1, 1);
    LGKM(3); PRIO1; MM6(avA, bv0, 3); PRIO0;
    // p8: readahead switches to next-iteration b0
    BAR(); stgB(1, kC, 1); stgA(0, kC, 1);
    LDA6(avA, 0, 0, 0); LDB4(bv0, 0, 0);
    LGKM(7); PRIO1; MM6(avB, bv1, 3); PRIO0;
  }

  // peeled final iteration: tiles 14 (b0), 15 (b1); no staging past t15
  {
    BAR(); stgA(1, 15, 1);
    LDA6(avB, 0, 1, 0); LDB4(bv1, 1, 0);
    LGKM(7); PRIO1; MM6(avA, bv0, 0); PRIO0;

    BAR(); stgA(2, 15, 1);
    LDA6(avA, 3, 0, 0);
    LGKM(3); PRIO1; MM6(avB, bv1, 0); PRIO0;

    BAR(); VMC(0);
    LDA6(avB, 3, 1, 0);
    LGKM(3); PRIO1; MM6(avA, bv0, 3); PRIO0;

    BAR();
    LDA6(avA, 0, 0, 1); LDB4(bv0, 0, 1);
    LGKM(7); PRIO1; MM6(avB, bv1, 3); PRIO0;

    BAR();
    LDA6(avB, 0, 1, 1); LDB4(bv1, 1, 1);
    LGKM(7); PRIO1; MM6(avA, bv0, 0); PRIO0;

    BAR();
    LDA6(avA, 3, 0, 1);
    LGKM(3); PRIO1; MM6(avB, bv1, 0); PRIO0;

    BAR();
    LDA6(avB, 3, 1, 1);
    LGKM(3); PRIO1; MM6(avA, bv0, 3); PRIO0;

    BAR();
    LGKM(0); PRIO1; MM6(avB, bv1, 3); PRIO0;
  }

  // epilogue: bf16 C, ldc 2048
  #pragma unroll
  for (int f = 0; f < 6; ++f) {
    #pragma unroll
    for (int j = 0; j < 4; ++j) {
      const int r = row0 + (2 * f + wm) * 16 + lq * 4 + j;
      short* cp = C + (size_t)r * 2048 + col0 + wn * 64 + lr;
      #pragma unroll
      for (int g = 0; g < 4; ++g)
        cp[g * 16] = f2bf(acc[f][g][j]);
    }
  }
}

// One wave per (bi, n, h). Fuses q/k/v ray rotation, scores, softmax, PV,
// inverse rotation. q fp32 in, kv bf16 in, out bf16 (feeds OUT-GEMM).
__global__ __launch_bounds__(256)
void attn_kernel(const float* __restrict__ dray,
                 const int* __restrict__ bfid, const int* __restrict__ blid,
                 const int* __restrict__ bsid,
                 const int* __restrict__ nfid, const int* __restrict__ ntid,
                 const int* __restrict__ nlid, const int* __restrict__ nsid,
                 const int* __restrict__ nmask,
                 const float* __restrict__ qbuf,
                 const __hip_bfloat16* __restrict__ kvbuf,
                 __hip_bfloat16* __restrict__ obuf)
{
  const int lane = threadIdx.x & 63;
  const int gw   = blockIdx.x * 4 + (threadIdx.x >> 6);
  const int h    = gw & (H - 1);
  const int bn   = gw >> 4;
  const int n    = bn % NB;

  int st = clampi(bsid[n], 0, STAGES - 1);
  int f  = clampi(bfid[n], 0, FG - 1);
  int lc = clampi(blid[n], 0, L - 1);
  const float* dqp = dray + ((size_t)(st * FG + f) * L + lc) * 9;
  float dq[9];
  #pragma unroll
  for (int t = 0; t < 9; ++t) dq[t] = dqp[t];

  const float qraw = qbuf[(size_t)bn * ADIM + h * HD + lane];
  const int rr = lane & 15;

  float x0 = __shfl(qraw, rr), x1 = __shfl(qraw, 16 + rr), x2 = __shfl(qraw, 32 + rr);
  float q0 = dq[0]*x0 + dq[1]*x1 + dq[2]*x2;
  float q1 = dq[3]*x0 + dq[4]*x1 + dq[5]*x2;
  float q2 = dq[6]*x0 + dq[7]*x1 + dq[8]*x2;
  float qd = lane < 16 ? q0 : lane < 32 ? q1 : lane < 48 ? q2 : qraw;

  const __hip_bfloat16* kvb = kvbuf + (size_t)bn * MN * 2048 + h * HD;
  float s[MN], vd[MN];
  #pragma unroll
  for (int m = 0; m < MN; ++m) {
    const int idx = n * MN + m;
    int nst = clampi(nsid[idx], 0, STAGES - 1);
    int nfc = clampi(nfid[idx], 0, FG - 1);
    int nlc = clampi(nlid[idx], 0, L - 1);
    const float* dkp = dray + ((size_t)(nst * FG + nfc) * L + nlc) * 9;
    float dk[9];
    #pragma unroll
    for (int t = 0; t < 9; ++t) dk[t] = dkp[t];

    float kraw = __bfloat162float(kvb[(size_t)m * 2048 + lane]);
    float k0 = __shfl(kraw, rr), k1 = __shfl(kraw, 16 + rr), k2 = __shfl(kraw, 32 + rr);
    float kr0 = dk[0]*k0 + dk[1]*k1 + dk[2]*k2;
    float kr1 = dk[3]*k0 + dk[4]*k1 + dk[5]*k2;
    float kr2 = dk[6]*k0 + dk[7]*k1 + dk[8]*k2;
    float kd = lane < 16 ? kr0 : lane < 32 ? kr1 : lane < 48 ? kr2 : kraw;

    float p = qd * kd;
    #pragma unroll
    for (int off = 32; off; off >>= 1) p += __shfl_xor(p, off);
    s[m] = p;

    float vraw = __bfloat162float(kvb[(size_t)m * 2048 + 1024 + lane]);
    float v0 = __shfl(vraw, rr), v1 = __shfl(vraw, 16 + rr), v2 = __shfl(vraw, 32 + rr);
    float vr0 = dk[0]*v0 + dk[1]*v1 + dk[2]*v2;
    float vr1 = dk[3]*v0 + dk[4]*v1 + dk[5]*v2;
    float vr2 = dk[6]*v0 + dk[7]*v1 + dk[8]*v2;
    vd[m] = lane < 16 ? vr0 : lane < 32 ? vr1 : lane < 48 ? vr2 : vraw;
  }

  float mx = -INFINITY;
  #pragma unroll
  for (int m = 0; m < MN; ++m) {
    const int idx = n * MN + m;
    int nf = nfid[idx], nt = ntid[idx];
    bool ok = (nmask[idx] != 0) && nf >= 0 && nf < FG && nt >= 0 && nt < L;
    s[m] = ok ? s[m] * SCALE : -INFINITY;
    mx = fmaxf(mx, s[m]);
  }
  float den = 0.f;
  #pragma unroll
  for (int m = 0; m < MN; ++m) { s[m] = expf(s[m] - mx); den += s[m]; }
  float inv = 1.0f / den;

  float od = 0.f;
  #pragma unroll
  for (int m = 0; m < MN; ++m) od += s[m] * vd[m];
  od *= inv;

  float y0 = __shfl(od, rr), y1 = __shfl(od, 16 + rr), y2 = __shfl(od, 32 + rr);
  float t0 = dq[0]*y0 + dq[3]*y1 + dq[6]*y2;
  float t1 = dq[1]*y0 + dq[4]*y1 + dq[7]*y2;
  float t2 = dq[2]*y0 + dq[5]*y1 + dq[8]*y2;
  float outd = lane < 16 ? t0 : lane < 32 ? t1 : lane < 48 ? t2 : od;

  obuf[(size_t)bn * ADIM + h * HD + lane] = __float2bfloat16(outd);
}

extern "C" void kernel_launch(void* const* d_in, const int* in_sizes, int n_in,
                              void* d_out, int out_size, void* d_ws, size_t ws_size,
                              hipStream_t stream) {
  const float* x     = (const float*)d_in[0];
  const float* qkv_w = (const float*)d_in[1];
  const float* out_w = (const float*)d_in[2];
  const float* out_b = (const float*)d_in[3];
  const float* dray  = (const float*)d_in[4];
  const int* bfid  = (const int*)d_in[5];
  const int* btid  = (const int*)d_in[6];
  const int* blid  = (const int*)d_in[7];
  const int* bsid  = (const int*)d_in[8];
  const int* nfid  = (const int*)d_in[9];
  const int* ntid  = (const int*)d_in[10];
  const int* nlid  = (const int*)d_in[11];
  const int* nsid  = (const int*)d_in[12];
  const int* nmask = (const int*)d_in[13];

  char* ws = (char*)d_ws;
  short* xb    = (short*)(ws);                  // 12288*1024 bf16 = 25165824 B
  short* qwT   = (short*)(ws + 25165824);       // 3072*1024  bf16 =  6291456 B
  short* owT   = (short*)(ws + 31457280);       // 1024*1024  bf16 =  2097152 B
  float* qbuf  = (float*)(ws + 33554432);       // 1536*1024  f32  =  6291456 B
  short* kvbuf = (short*)(ws + 39845888);       // 12288*2048 bf16 = 50331648 B
  short* obuf  = (short*)(ws + 90177536);       // 1536*1024  bf16 =  3145728 B

  hipMemsetAsync(d_out, 0, (size_t)out_size * sizeof(float), stream);

  conv_bf16<<<6144, 256, 0, stream>>>(x, xb);
  transpose_conv<<<dim3(96, 32), 256, 0, stream>>>(qkv_w, qwT, 1024, 3072);
  transpose_conv<<<dim3(32, 32), 256, 0, stream>>>(out_w, owT, 1024, 1024);

  // Q projection: 1536 x 1024 x 1024 (m97 structure)
  mfma_gemm<0><<<dim3(8, 12), 256, 0, stream>>>(xb, qwT, qbuf, bfid, btid, nullptr);
  // KV projection: 12288 x 2048 x 1024 (192x256 read-ahead schedule)
  kv_gemm192<<<dim3(8, 64), 512, 0, stream>>>(xb, qwT, kvbuf, nfid, ntid);
  // fused rotations + attention
  attn_kernel<<<6144, 256, 0, stream>>>(dray, bfid, blid, bsid,
                                        nfid, ntid, nlid, nsid, nmask,
                                        qbuf, (const __hip_bfloat16*)kvbuf,
                                        (__hip_bfloat16*)obuf);
  // output projection + bias + valid mask + scatter: 1536 x 1024 x 1024
  mfma_gemm<2><<<dim3(8, 12), 256, 0, stream>>>(obuf, owT, d_out, bfid, btid, out_b);
}

// Round 6
// 179.569 us; speedup vs baseline: 1.0295x; 1.0082x over previous
//
#include <hip/hip_runtime.h>
#include <hip/hip_bf16.h>
#include <cstddef>

#define FG 6
#define L 1024
#define NB 768
#define MN 8
#define H 16
#define HD 64
#define ADIM 1024
#define STAGES 4
#define SCALE 0.125f

typedef __attribute__((ext_vector_type(8))) short bf16x8;
typedef __attribute__((ext_vector_type(4))) float f32x4;
typedef __attribute__((address_space(3))) short lds_short_t;
typedef const __attribute__((address_space(1))) short g_short_t;

__device__ __forceinline__ int clampi(int v, int lo, int hi) {
  return v < lo ? lo : (v > hi ? hi : v);
}

__device__ __forceinline__ short f2bf(float f) {
  __hip_bfloat16 h = __float2bfloat16(f);
  return *reinterpret_cast<short*>(&h);
}

__device__ __forceinline__ void gload16(const short* g, short* l) {
  __builtin_amdgcn_global_load_lds((g_short_t*)g, (lds_short_t*)l, 16, 0, 0);
}

// fp32 -> bf16 bulk convert (8 elems/thread)
__global__ __launch_bounds__(256)
void conv_bf16(const float* __restrict__ in, short* __restrict__ out) {
  size_t i = ((size_t)blockIdx.x * 256 + threadIdx.x) * 8;
  float4 a = *(const float4*)(in + i);
  float4 b = *(const float4*)(in + i + 4);
  bf16x8 v;
  v[0] = f2bf(a.x); v[1] = f2bf(a.y); v[2] = f2bf(a.z); v[3] = f2bf(a.w);
  v[4] = f2bf(b.x); v[5] = f2bf(b.y); v[6] = f2bf(b.z); v[7] = f2bf(b.w);
  *(bf16x8*)(out + i) = v;
}

// in fp32 [K][N] -> out bf16 [N][K]  (B^T layout for the GEMM)
__global__ __launch_bounds__(256)
void transpose_conv(const float* __restrict__ in, short* __restrict__ out,
                    int K, int N) {
  __shared__ float tile[32][33];
  const int n0 = blockIdx.x * 32, k0 = blockIdx.y * 32;
  const int tx = threadIdx.x & 31, ty = threadIdx.x >> 5;
  #pragma unroll
  for (int i = 0; i < 4; ++i)
    tile[ty + i * 8][tx] = in[(size_t)(k0 + ty + i * 8) * N + n0 + tx];
  __syncthreads();
  #pragma unroll
  for (int i = 0; i < 4; ++i)
    out[(size_t)(n0 + ty + i * 8) * K + k0 + tx] =
        f2bf(tile[tx][ty + i * 8]);
}

// ============ 192x256 read-ahead counted-lgkm QKV-GEMM ====================
// KV blocks (blockIdx.y < 64): M=12288 gathered via nfid/ntid, B-window
//   [1024,3072), C=kvbuf bf16 ldc2048.
// Q blocks (blockIdx.y >= 64, blockIdx.x < 4): M=1536 gathered via
//   bfid/btid, B-window [0,1024), C=qbuf fp32 ldc1024.
// 8 waves (2M x 4N), wave tile 96x64 (6 M-frags). One barrier per phase;
// ds_reads for cluster p+1 issued BEFORE cluster p's MFMA, waited with
// counted lgkmcnt -> LDS drain overlaps MFMA. vmcnt(2) only at p3/p7, one
// phase before the staged data's first read. LDS: A [2buf][192][64],
// B [2buf][256][64], slot ^= (row&7): conflict-free.

#define BAR()   do { __builtin_amdgcn_s_barrier(); __builtin_amdgcn_sched_barrier(0); } while (0)
#define LGKM(N) do { asm volatile("s_waitcnt lgkmcnt(" #N ")" ::: "memory"); __builtin_amdgcn_sched_barrier(0); } while (0)
#define VMC(N)  do { asm volatile("s_waitcnt vmcnt(" #N ")" ::: "memory"); __builtin_amdgcn_sched_barrier(0); } while (0)
#define PRIO1   __builtin_amdgcn_s_setprio(1)
#define PRIO0   __builtin_amdgcn_s_setprio(0)

#define LDA6(D, FB, KK, BUF)                                                  \
  { _Pragma("unroll")                                                         \
    for (int f_ = 0; f_ < 3; ++f_) {                                          \
      const int row_ = (2 * ((FB) + f_) + wm) * 16 + lr;                      \
      D[f_] = *(const bf16x8*)(As8 + (BUF) * 24576 + row_ * 128               \
               + ((((KK) * 4 + lq) ^ swz) << 4));                             \
    } }

#define LDB4(D, KK, BUF)                                                      \
  { _Pragma("unroll")                                                         \
    for (int g_ = 0; g_ < 4; ++g_) {                                          \
      const int row_ = wn * 64 + g_ * 16 + lr;                                \
      D[g_] = *(const bf16x8*)(Bs8 + (BUF) * 32768 + row_ * 128               \
               + ((((KK) * 4 + lq) ^ swz) << 4));                             \
    } }

#define MM6(AV, BV, FB)                                                       \
  { _Pragma("unroll")                                                         \
    for (int f_ = 0; f_ < 3; ++f_)                                            \
      _Pragma("unroll")                                                       \
      for (int g_ = 0; g_ < 4; ++g_)                                          \
        acc[(FB) + f_][g_] = __builtin_amdgcn_mfma_f32_16x16x32_bf16(         \
            AV[f_], BV[g_], acc[(FB) + f_][g_], 0, 0, 0); }

__global__ __launch_bounds__(512, 2)
void qkv_gemm192(const short* __restrict__ A, const short* __restrict__ B,
                 short* __restrict__ Ckv, float* __restrict__ Cq,
                 const int* __restrict__ nfid, const int* __restrict__ ntid,
                 const int* __restrict__ bfid, const int* __restrict__ btid)
{
  __shared__ __align__(16) short As[24576];   // 2 x 192 x 64 = 48 KiB
  __shared__ __align__(16) short Bs[32768];   // 2 x 256 x 64 = 64 KiB

  const bool isQ = blockIdx.y >= 64;
  if (isQ && blockIdx.x >= 4) return;         // dead corner blocks

  const int tid = threadIdx.x;
  const int w = tid >> 6, lane = tid & 63;
  const int wm = w >> 2, wn = w & 3;
  const int lr = lane & 15, lq = lane >> 4;
  const int row0 = (isQ ? (blockIdx.y - 64) : blockIdx.y) * 192;
  const int col0 = blockIdx.x * 256;
  const int bcol0 = isQ ? 0 : 1024;
  const int* fi = isQ ? bfid : nfid;
  const int* ti = isQ ? btid : ntid;
  const int MROW = isQ ? NB : NB * MN;

  // inverse-swizzled source offset (elements)
  const int ssrc = (((tid & 7) ^ ((tid >> 3) & 7))) * 8;

  size_t a_src[3];
  #pragma unroll
  for (int c = 0; c < 3; ++c) {
    const int rr = row0 + c * 64 + (tid >> 3);
    const int bi = rr >= MROW;
    const int idx = rr - bi * MROW;
    const int f = clampi(fi[idx], 0, FG - 1);
    const int q = clampi(ti[idx], 0, L - 1);
    a_src[c] = (size_t)((bi * FG + f) * L + q) * 1024 + ssrc;
  }
  size_t b_src[2][2];
  #pragma unroll
  for (int h = 0; h < 2; ++h)
    #pragma unroll
    for (int i = 0; i < 2; ++i)
      b_src[h][i] = (size_t)(bcol0 + col0 + h * 128 + ((tid + i * 512) >> 3)) * 1024 + ssrc;

  auto stgA = [&](int c, int kt, int buf) {
    gload16(A + a_src[c] + kt * 64, As + buf * 12288 + c * 4096 + tid * 8);
  };
  auto stgB = [&](int h, int kt, int buf) {
    gload16(B + b_src[h][0] + kt * 64, Bs + buf * 16384 + h * 8192 + tid * 8);
    gload16(B + b_src[h][1] + kt * 64, Bs + buf * 16384 + h * 8192 + 4096 + tid * 8);
  };

  const char* As8 = (const char*)As;
  const char* Bs8 = (const char*)Bs;
  const int swz = lane & 7;

  f32x4 acc[6][4];
  #pragma unroll
  for (int f = 0; f < 6; ++f)
    #pragma unroll
    for (int g = 0; g < 4; ++g) acc[f][g] = (f32x4){0.f, 0.f, 0.f, 0.f};

  bf16x8 avA[3], avB[3], bv0[4], bv1[4];

  // prologue: t0 full (7 ops) + t1 B,Ac0 (5 ops); wait t0; pre-issue c(p1)
  stgB(0, 0, 0); stgB(1, 0, 0); stgA(0, 0, 0); stgA(1, 0, 0); stgA(2, 0, 0);
  stgB(0, 1, 1); stgB(1, 1, 1); stgA(0, 1, 1);
  VMC(5); BAR();
  LDA6(avA, 0, 0, 0); LDB4(bv0, 0, 0);

  for (int I = 0; I < 7; ++I) {
    const int kA = 2 * I + 1, kB = 2 * I + 2, kC = 2 * I + 3;
    // p1
    BAR(); stgA(1, kA, 1);
    LDA6(avB, 0, 1, 0); LDB4(bv1, 1, 0);
    LGKM(7); PRIO1; MM6(avA, bv0, 0); PRIO0;
    // p2
    BAR(); stgA(2, kA, 1);
    LDA6(avA, 3, 0, 0);
    LGKM(3); PRIO1; MM6(avB, bv1, 0); PRIO0;
    // p3
    BAR(); stgB(0, kB, 0); VMC(2);
    LDA6(avB, 3, 1, 0);
    LGKM(3); PRIO1; MM6(avA, bv0, 3); PRIO0;
    // p4
    BAR(); stgB(1, kB, 0); stgA(0, kB, 0);
    LDA6(avA, 0, 0, 1); LDB4(bv0, 0, 1);
    LGKM(7); PRIO1; MM6(avB, bv1, 3); PRIO0;
    // p5
    BAR(); stgA(1, kB, 0);
    LDA6(avB, 0, 1, 1); LDB4(bv1, 1, 1);
    LGKM(7); PRIO1; MM6(avA, bv0, 0); PRIO0;
    // p6
    BAR(); stgA(2, kB, 0);
    LDA6(avA, 3, 0, 1);
    LGKM(3); PRIO1; MM6(avB, bv1, 0); PRIO0;
    // p7
    BAR(); stgB(0, kC, 1); VMC(2);
    LDA6(avB, 3, 1, 1);
    LGKM(3); PRIO1; MM6(avA, bv0, 3); PRIO0;
    // p8
    BAR(); stgB(1, kC, 1); stgA(0, kC, 1);
    LDA6(avA, 0, 0, 0); LDB4(bv0, 0, 0);
    LGKM(7); PRIO1; MM6(avB, bv1, 3); PRIO0;
  }

  // peeled final iteration: tiles 14 (b0), 15 (b1); no staging past t15
  {
    BAR(); stgA(1, 15, 1);
    LDA6(avB, 0, 1, 0); LDB4(bv1, 1, 0);
    LGKM(7); PRIO1; MM6(avA, bv0, 0); PRIO0;

    BAR(); stgA(2, 15, 1);
    LDA6(avA, 3, 0, 0);
    LGKM(3); PRIO1; MM6(avB, bv1, 0); PRIO0;

    BAR(); VMC(0);
    LDA6(avB, 3, 1, 0);
    LGKM(3); PRIO1; MM6(avA, bv0, 3); PRIO0;

    BAR();
    LDA6(avA, 0, 0, 1); LDB4(bv0, 0, 1);
    LGKM(7); PRIO1; MM6(avB, bv1, 3); PRIO0;

    BAR();
    LDA6(avB, 0, 1, 1); LDB4(bv1, 1, 1);
    LGKM(7); PRIO1; MM6(avA, bv0, 0); PRIO0;

    BAR();
    LDA6(avA, 3, 0, 1);
    LGKM(3); PRIO1; MM6(avB, bv1, 0); PRIO0;

    BAR();
    LDA6(avB, 3, 1, 1);
    LGKM(3); PRIO1; MM6(avA, bv0, 3); PRIO0;

    BAR();
    LGKM(0); PRIO1; MM6(avB, bv1, 3); PRIO0;
  }

  // epilogue
  if (!isQ) {
    #pragma unroll
    for (int f = 0; f < 6; ++f) {
      #pragma unroll
      for (int j = 0; j < 4; ++j) {
        const int r = row0 + (2 * f + wm) * 16 + lq * 4 + j;
        short* cp = Ckv + (size_t)r * 2048 + col0 + wn * 64 + lr;
        #pragma unroll
        for (int g = 0; g < 4; ++g)
          cp[g * 16] = f2bf(acc[f][g][j]);
      }
    }
  } else {
    #pragma unroll
    for (int f = 0; f < 6; ++f) {
      #pragma unroll
      for (int j = 0; j < 4; ++j) {
        const int r = row0 + (2 * f + wm) * 16 + lq * 4 + j;
        float* cp = Cq + (size_t)r * 1024 + col0 + wn * 64 + lr;
        #pragma unroll
        for (int g = 0; g < 4; ++g)
          cp[g * 16] = acc[f][g][j];
      }
    }
  }
}

// ============ 64x128 m97-structure OUT-GEMM (192 blocks) ==================
// A=obuf bf16 direct rows, B=owT, C=d_out fp32 with bias+valid+scatter.
__global__ __launch_bounds__(256)
void out_gemm64(const short* __restrict__ A, const short* __restrict__ B,
                float* __restrict__ C,
                const int* __restrict__ f_ids, const int* __restrict__ t_ids,
                const float* __restrict__ bias)
{
  __shared__ __align__(16) short As[4096];    // 64 x 64
  __shared__ __align__(16) short Bs[8192];    // 128 x 64

  const int tid = threadIdx.x;
  const int w = tid >> 6, lane = tid & 63;
  const int row0 = blockIdx.y * 64, col0 = blockIdx.x * 128;
  const int lr = lane & 15, lq = lane >> 4;
  const int wrow = (w >> 1) * 32, wcol = (w & 1) * 64;

  size_t asrc[2]; short* adst[2];
  #pragma unroll
  for (int c = 0; c < 2; ++c) {
    const int d = c * 256 + tid, r = d >> 3;
    const int ss = (d & 7) ^ (r & 7);
    asrc[c] = (size_t)(row0 + r) * 1024 + ss * 8;
    adst[c] = As + d * 8;
  }
  size_t bsrc[4]; short* bdst[4];
  #pragma unroll
  for (int c = 0; c < 4; ++c) {
    const int d = c * 256 + tid, r = d >> 3;
    const int ss = (d & 7) ^ (r & 7);
    bsrc[c] = (size_t)(col0 + r) * 1024 + ss * 8;
    bdst[c] = Bs + d * 8;
  }

  const char* As8 = (const char*)As;
  const char* Bs8 = (const char*)Bs;
  const int swz = lr & 7;

  f32x4 acc[2][4];
  #pragma unroll
  for (int m = 0; m < 2; ++m)
    #pragma unroll
    for (int n = 0; n < 4; ++n) acc[m][n] = (f32x4){0.f, 0.f, 0.f, 0.f};

  for (int kt = 0; kt < 16; ++kt) {
    #pragma unroll
    for (int c = 0; c < 2; ++c) gload16(A + asrc[c] + kt * 64, adst[c]);
    #pragma unroll
    for (int c = 0; c < 4; ++c) gload16(B + bsrc[c] + kt * 64, bdst[c]);
    __syncthreads();
    #pragma unroll
    for (int kk = 0; kk < 2; ++kk) {
      const int so = ((kk * 4 + lq) ^ swz) << 4;
      bf16x8 av[2], bv[4];
      #pragma unroll
      for (int m = 0; m < 2; ++m)
        av[m] = *(const bf16x8*)(As8 + (wrow + m * 16 + lr) * 128 + so);
      #pragma unroll
      for (int n = 0; n < 4; ++n)
        bv[n] = *(const bf16x8*)(Bs8 + (wcol + n * 16 + lr) * 128 + so);
      #pragma unroll
      for (int m = 0; m < 2; ++m)
        #pragma unroll
        for (int n = 0; n < 4; ++n)
          acc[m][n] = __builtin_amdgcn_mfma_f32_16x16x32_bf16(
              av[m], bv[n], acc[m][n], 0, 0, 0);
    }
    __syncthreads();
  }

  float bb[4];
  #pragma unroll
  for (int n = 0; n < 4; ++n) bb[n] = bias[col0 + wcol + n * 16 + lr];
  #pragma unroll
  for (int m = 0; m < 2; ++m)
    #pragma unroll
    for (int j = 0; j < 4; ++j) {
      const int r  = row0 + wrow + m * 16 + lq * 4 + j;
      const int bi = r >= NB;
      const int nn = r - bi * NB;
      const int bf = f_ids[nn], bt = t_ids[nn];
      const int qf = clampi(bf, 0, FG - 1), qi = clampi(bt, 0, L - 1);
      const bool valid = (bf == qf) && (bt == qi);
      const size_t obase = ((size_t)(bi * FG + qf) * L + qi) * 1024;
      #pragma unroll
      for (int n = 0; n < 4; ++n) {
        const int col = col0 + wcol + n * 16 + lr;
        C[obase + col] = valid ? (acc[m][n][j] + bb[n]) : 0.f;
      }
    }
}

// One wave per (bi, n, h). Fuses q/k/v ray rotation, scores, softmax, PV,
// inverse rotation. q fp32 in, kv bf16 in, out bf16 (feeds OUT-GEMM).
__global__ __launch_bounds__(256)
void attn_kernel(const float* __restrict__ dray,
                 const int* __restrict__ bfid, const int* __restrict__ blid,
                 const int* __restrict__ bsid,
                 const int* __restrict__ nfid, const int* __restrict__ ntid,
                 const int* __restrict__ nlid, const int* __restrict__ nsid,
                 const int* __restrict__ nmask,
                 const float* __restrict__ qbuf,
                 const __hip_bfloat16* __restrict__ kvbuf,
                 __hip_bfloat16* __restrict__ obuf)
{
  const int lane = threadIdx.x & 63;
  const int gw   = blockIdx.x * 4 + (threadIdx.x >> 6);
  const int h    = gw & (H - 1);
  const int bn   = gw >> 4;
  const int n    = bn % NB;

  int st = clampi(bsid[n], 0, STAGES - 1);
  int f  = clampi(bfid[n], 0, FG - 1);
  int lc = clampi(blid[n], 0, L - 1);
  const float* dqp = dray + ((size_t)(st * FG + f) * L + lc) * 9;
  float dq[9];
  #pragma unroll
  for (int t = 0; t < 9; ++t) dq[t] = dqp[t];

  const float qraw = qbuf[(size_t)bn * ADIM + h * HD + lane];
  const int rr = lane & 15;

  float x0 = __shfl(qraw, rr), x1 = __shfl(qraw, 16 + rr), x2 = __shfl(qraw, 32 + rr);
  float q0 = dq[0]*x0 + dq[1]*x1 + dq[2]*x2;
  float q1 = dq[3]*x0 + dq[4]*x1 + dq[5]*x2;
  float q2 = dq[6]*x0 + dq[7]*x1 + dq[8]*x2;
  float qd = lane < 16 ? q0 : lane < 32 ? q1 : lane < 48 ? q2 : qraw;

  const __hip_bfloat16* kvb = kvbuf + (size_t)bn * MN * 2048 + h * HD;
  float s[MN], vd[MN];
  #pragma unroll
  for (int m = 0; m < MN; ++m) {
    const int idx = n * MN + m;
    int nst = clampi(nsid[idx], 0, STAGES - 1);
    int nfc = clampi(nfid[idx], 0, FG - 1);
    int nlc = clampi(nlid[idx], 0, L - 1);
    const float* dkp = dray + ((size_t)(nst * FG + nfc) * L + nlc) * 9;
    float dk[9];
    #pragma unroll
    for (int t = 0; t < 9; ++t) dk[t] = dkp[t];

    float kraw = __bfloat162float(kvb[(size_t)m * 2048 + lane]);
    float k0 = __shfl(kraw, rr), k1 = __shfl(kraw, 16 + rr), k2 = __shfl(kraw, 32 + rr);
    float kr0 = dk[0]*k0 + dk[1]*k1 + dk[2]*k2;
    float kr1 = dk[3]*k0 + dk[4]*k1 + dk[5]*k2;
    float kr2 = dk[6]*k0 + dk[7]*k1 + dk[8]*k2;
    float kd = lane < 16 ? kr0 : lane < 32 ? kr1 : lane < 48 ? kr2 : kraw;

    float p = qd * kd;
    #pragma unroll
    for (int off = 32; off; off >>= 1) p += __shfl_xor(p, off);
    s[m] = p;

    float vraw = __bfloat162float(kvb[(size_t)m * 2048 + 1024 + lane]);
    float v0 = __shfl(vraw, rr), v1 = __shfl(vraw, 16 + rr), v2 = __shfl(vraw, 32 + rr);
    float vr0 = dk[0]*v0 + dk[1]*v1 + dk[2]*v2;
    float vr1 = dk[3]*v0 + dk[4]*v1 + dk[5]*v2;
    float vr2 = dk[6]*v0 + dk[7]*v1 + dk[8]*v2;
    vd[m] = lane < 16 ? vr0 : lane < 32 ? vr1 : lane < 48 ? vr2 : vraw;
  }

  float mx = -INFINITY;
  #pragma unroll
  for (int m = 0; m < MN; ++m) {
    const int idx = n * MN + m;
    int nf = nfid[idx], nt = ntid[idx];
    bool ok = (nmask[idx] != 0) && nf >= 0 && nf < FG && nt >= 0 && nt < L;
    s[m] = ok ? s[m] * SCALE : -INFINITY;
    mx = fmaxf(mx, s[m]);
  }
  float den = 0.f;
  #pragma unroll
  for (int m = 0; m < MN; ++m) { s[m] = expf(s[m] - mx); den += s[m]; }
  float inv = 1.0f / den;

  float od = 0.f;
  #pragma unroll
  for (int m = 0; m < MN; ++m) od += s[m] * vd[m];
  od *= inv;

  float y0 = __shfl(od, rr), y1 = __shfl(od, 16 + rr), y2 = __shfl(od, 32 + rr);
  float t0 = dq[0]*y0 + dq[3]*y1 + dq[6]*y2;
  float t1 = dq[1]*y0 + dq[4]*y1 + dq[7]*y2;
  float t2 = dq[2]*y0 + dq[5]*y1 + dq[8]*y2;
  float outd = lane < 16 ? t0 : lane < 32 ? t1 : lane < 48 ? t2 : od;

  obuf[(size_t)bn * ADIM + h * HD + lane] = __float2bfloat16(outd);
}

extern "C" void kernel_launch(void* const* d_in, const int* in_sizes, int n_in,
                              void* d_out, int out_size, void* d_ws, size_t ws_size,
                              hipStream_t stream) {
  const float* x     = (const float*)d_in[0];
  const float* qkv_w = (const float*)d_in[1];
  const float* out_w = (const float*)d_in[2];
  const float* out_b = (const float*)d_in[3];
  const float* dray  = (const float*)d_in[4];
  const int* bfid  = (const int*)d_in[5];
  const int* btid  = (const int*)d_in[6];
  const int* blid  = (const int*)d_in[7];
  const int* bsid  = (const int*)d_in[8];
  const int* nfid  = (const int*)d_in[9];
  const int* ntid  = (const int*)d_in[10];
  const int* nlid  = (const int*)d_in[11];
  const int* nsid  = (const int*)d_in[12];
  const int* nmask = (const int*)d_in[13];

  char* ws = (char*)d_ws;
  short* xb    = (short*)(ws);                  // 12288*1024 bf16 = 25165824 B
  short* qwT   = (short*)(ws + 25165824);       // 3072*1024  bf16 =  6291456 B
  short* owT   = (short*)(ws + 31457280);       // 1024*1024  bf16 =  2097152 B
  float* qbuf  = (float*)(ws + 33554432);       // 1536*1024  f32  =  6291456 B
  short* kvbuf = (short*)(ws + 39845888);       // 12288*2048 bf16 = 50331648 B
  short* obuf  = (short*)(ws + 90177536);       // 1536*1024  bf16 =  3145728 B

  (void)hipMemsetAsync(d_out, 0, (size_t)out_size * sizeof(float), stream);

  conv_bf16<<<6144, 256, 0, stream>>>(x, xb);
  transpose_conv<<<dim3(96, 32), 256, 0, stream>>>(qkv_w, qwT, 1024, 3072);
  transpose_conv<<<dim3(32, 32), 256, 0, stream>>>(out_w, owT, 1024, 1024);

  // Q (y=64..71, x<4) + KV (y=0..63) projections in one dispatch
  qkv_gemm192<<<dim3(8, 72), 512, 0, stream>>>(xb, qwT, kvbuf, qbuf,
                                               nfid, ntid, bfid, btid);
  // fused rotations + attention
  attn_kernel<<<6144, 256, 0, stream>>>(dray, bfid, blid, bsid,
                                        nfid, ntid, nlid, nsid, nmask,
                                        qbuf, (const __hip_bfloat16*)kvbuf,
                                        (__hip_bfloat16*)obuf);
  // output projection + bias + valid mask + scatter: 1536 x 1024 x 1024
  out_gemm64<<<dim3(8, 24), 256, 0, stream>>>(obuf, owT, (float*)d_out,
                                              bfid, btid, out_b);
}

// Round 7
// 176.442 us; speedup vs baseline: 1.0478x; 1.0177x over previous
//
#include <hip/hip_runtime.h>
#include <hip/hip_bf16.h>
#include <cstddef>

#define FG 6
#define L 1024
#define NB 768
#define MN 8
#define H 16
#define HD 64
#define ADIM 1024
#define STAGES 4
#define SCALE 0.125f

typedef __attribute__((ext_vector_type(8))) short bf16x8;
typedef __attribute__((ext_vector_type(4))) float f32x4;
typedef __attribute__((address_space(3))) short lds_short_t;
typedef const __attribute__((address_space(1))) short g_short_t;

__device__ __forceinline__ int clampi(int v, int lo, int hi) {
  return v < lo ? lo : (v > hi ? hi : v);
}

__device__ __forceinline__ short f2bf(float f) {
  __hip_bfloat16 h = __float2bfloat16(f);
  return *reinterpret_cast<short*>(&h);
}

__device__ __forceinline__ void gload16(const short* g, short* l) {
  __builtin_amdgcn_global_load_lds((g_short_t*)g, (lds_short_t*)l, 16, 0, 0);
}

// fp32 -> bf16 bulk convert (8 elems/thread)
__global__ __launch_bounds__(256)
void conv_bf16(const float* __restrict__ in, short* __restrict__ out) {
  size_t i = ((size_t)blockIdx.x * 256 + threadIdx.x) * 8;
  float4 a = *(const float4*)(in + i);
  float4 b = *(const float4*)(in + i + 4);
  bf16x8 v;
  v[0] = f2bf(a.x); v[1] = f2bf(a.y); v[2] = f2bf(a.z); v[3] = f2bf(a.w);
  v[4] = f2bf(b.x); v[5] = f2bf(b.y); v[6] = f2bf(b.z); v[7] = f2bf(b.w);
  *(bf16x8*)(out + i) = v;
}

// z=0: qkv_w (1024x3072) -> qwT (3072x1024); z=1 (x<32): out_w -> owT
__global__ __launch_bounds__(256)
void transpose_both(const float* __restrict__ qkv_w, short* __restrict__ qwT,
                    const float* __restrict__ out_w, short* __restrict__ owT) {
  const int z = blockIdx.z;
  if (z == 1 && blockIdx.x >= 32) return;
  const float* in = z ? out_w : qkv_w;
  short* out = z ? owT : qwT;
  const int N = z ? 1024 : 3072;
  __shared__ float tile[32][33];
  const int n0 = blockIdx.x * 32, k0 = blockIdx.y * 32;
  const int tx = threadIdx.x & 31, ty = threadIdx.x >> 5;
  #pragma unroll
  for (int i = 0; i < 4; ++i)
    tile[ty + i * 8][tx] = in[(size_t)(k0 + ty + i * 8) * N + n0 + tx];
  __syncthreads();
  #pragma unroll
  for (int i = 0; i < 4; ++i)
    out[(size_t)(n0 + ty + i * 8) * 1024 + k0 + tx] =
        f2bf(tile[tx][ty + i * 8]);
}

// ===================== 128x128 m97-structure Q-GEMM (proven r2-r4) ========
// A=xb gathered (bfid,btid), B=qwT[0:1024), C=qbuf fp32 ldc1024
__global__ __launch_bounds__(256)
void q_gemm128(const short* __restrict__ A, const short* __restrict__ B,
               float* __restrict__ C,
               const int* __restrict__ f_ids, const int* __restrict__ t_ids)
{
  __shared__ __align__(16) short As[8192];     // 128 rows x 64 bf16 (swizzled)
  __shared__ __align__(16) short Bs[8192];

  const int tid  = threadIdx.x;
  const int w    = tid >> 6, lane = tid & 63;
  const int row0 = blockIdx.y * 128, col0 = blockIdx.x * 128;

  size_t aoff[4], boff[4];
  short *adst[4], *bdst[4];
  #pragma unroll
  for (int c = 0; c < 4; ++c) {
    const int d = (w * 4 + c) * 64 + lane;
    const int r = d >> 3;
    const int ssrc = (d & 7) ^ (r & 7);
    const int rr = row0 + r;
    const int bi = rr >= NB;
    const int idx = rr - bi * NB;
    const int f = clampi(f_ids[idx], 0, FG - 1);
    const int q = clampi(t_ids[idx], 0, L - 1);
    const long gr = (long)(bi * FG + f) * L + q;
    aoff[c] = (size_t)gr * 1024 + ssrc * 8;
    boff[c] = (size_t)(col0 + r) * 1024 + ssrc * 8;
    adst[c] = As + (w * 4 + c) * 512;
    bdst[c] = Bs + (w * 4 + c) * 512;
  }

  const int lr = lane & 15, lq = lane >> 4;
  const int wrow = (w >> 1) * 64, wcol = (w & 1) * 64;
  const int sA = lr & 7;
  const char* As8 = (const char*)As;
  const char* Bs8 = (const char*)Bs;
  const int abase = (wrow + lr) * 128;
  const int bbase = (wcol + lr) * 128;

  f32x4 acc[4][4];
  #pragma unroll
  for (int m = 0; m < 4; ++m)
    #pragma unroll
    for (int n = 0; n < 4; ++n) acc[m][n] = (f32x4){0.f, 0.f, 0.f, 0.f};

  for (int kt = 0; kt < 16; ++kt) {
    #pragma unroll
    for (int c = 0; c < 4; ++c) {
      gload16(A + aoff[c] + kt * 64, adst[c]);
      gload16(B + boff[c] + kt * 64, bdst[c]);
    }
    __syncthreads();
    #pragma unroll
    for (int kk = 0; kk < 2; ++kk) {
      const int so = ((kk * 4 + lq) ^ sA) << 4;
      bf16x8 av[4], bv[4];
      #pragma unroll
      for (int m = 0; m < 4; ++m)
        av[m] = *(const bf16x8*)(As8 + abase + m * 2048 + so);
      #pragma unroll
      for (int n = 0; n < 4; ++n)
        bv[n] = *(const bf16x8*)(Bs8 + bbase + n * 2048 + so);
      #pragma unroll
      for (int m = 0; m < 4; ++m)
        #pragma unroll
        for (int n = 0; n < 4; ++n)
          acc[m][n] = __builtin_amdgcn_mfma_f32_16x16x32_bf16(
              av[m], bv[n], acc[m][n], 0, 0, 0);
    }
    __syncthreads();
  }

  #pragma unroll
  for (int m = 0; m < 4; ++m)
    #pragma unroll
    for (int j = 0; j < 4; ++j) {
      const int r = row0 + wrow + m * 16 + lq * 4 + j;
      #pragma unroll
      for (int n = 0; n < 4; ++n)
        C[(size_t)r * 1024 + col0 + wcol + n * 16 + lr] = acc[m][n][j];
    }
}

// ============ 192x256 read-ahead counted-lgkm KV-GEMM (proven r4) =========
// M=12288 gathered, N=2048 (qkv_w cols 1024..3071), K=1024. Grid 8x64 = 512
// blocks = exactly 2 rounds on 256 CUs (1 block/CU at 112 KiB LDS).

#define BAR()   do { __builtin_amdgcn_s_barrier(); __builtin_amdgcn_sched_barrier(0); } while (0)
#define LGKM(N) do { asm volatile("s_waitcnt lgkmcnt(" #N ")" ::: "memory"); __builtin_amdgcn_sched_barrier(0); } while (0)
#define VMC(N)  do { asm volatile("s_waitcnt vmcnt(" #N ")" ::: "memory"); __builtin_amdgcn_sched_barrier(0); } while (0)
#define PRIO1   __builtin_amdgcn_s_setprio(1)
#define PRIO0   __builtin_amdgcn_s_setprio(0)

#define LDA6(D, FB, KK, BUF)                                                  \
  { _Pragma("unroll")                                                         \
    for (int f_ = 0; f_ < 3; ++f_) {                                          \
      const int row_ = (2 * ((FB) + f_) + wm) * 16 + lr;                      \
      D[f_] = *(const bf16x8*)(As8 + (BUF) * 24576 + row_ * 128               \
               + ((((KK) * 4 + lq) ^ swz) << 4));                             \
    } }

#define LDB4(D, KK, BUF)                                                      \
  { _Pragma("unroll")                                                         \
    for (int g_ = 0; g_ < 4; ++g_) {                                          \
      const int row_ = wn * 64 + g_ * 16 + lr;                                \
      D[g_] = *(const bf16x8*)(Bs8 + (BUF) * 32768 + row_ * 128               \
               + ((((KK) * 4 + lq) ^ swz) << 4));                             \
    } }

#define MM6(AV, BV, FB)                                                       \
  { _Pragma("unroll")                                                         \
    for (int f_ = 0; f_ < 3; ++f_)                                            \
      _Pragma("unroll")                                                       \
      for (int g_ = 0; g_ < 4; ++g_)                                          \
        acc[(FB) + f_][g_] = __builtin_amdgcn_mfma_f32_16x16x32_bf16(         \
            AV[f_], BV[g_], acc[(FB) + f_][g_], 0, 0, 0); }

__global__ __launch_bounds__(512, 2)
void kv_gemm192(const short* __restrict__ A, const short* __restrict__ B,
                short* __restrict__ C,
                const int* __restrict__ f_ids, const int* __restrict__ t_ids)
{
  __shared__ __align__(16) short As[24576];   // 2 x 192 x 64 = 48 KiB
  __shared__ __align__(16) short Bs[32768];   // 2 x 256 x 64 = 64 KiB

  const int tid = threadIdx.x;
  const int w = tid >> 6, lane = tid & 63;
  const int wm = w >> 2, wn = w & 3;
  const int lr = lane & 15, lq = lane >> 4;
  const int row0 = blockIdx.y * 192;
  const int col0 = blockIdx.x * 256;

  // inverse-swizzled source offset (elements); same for A chunks & B halves
  const int ssrc = (((tid & 7) ^ ((tid >> 3) & 7))) * 8;

  size_t a_src[3];
  #pragma unroll
  for (int c = 0; c < 3; ++c) {
    const int rr = row0 + c * 64 + (tid >> 3);
    const int bi = rr >= NB * MN;
    const int idx = rr - bi * (NB * MN);
    const int f = clampi(f_ids[idx], 0, FG - 1);
    const int q = clampi(t_ids[idx], 0, L - 1);
    a_src[c] = (size_t)((bi * FG + f) * L + q) * 1024 + ssrc;
  }
  size_t b_src[2][2];
  #pragma unroll
  for (int h = 0; h < 2; ++h)
    #pragma unroll
    for (int i = 0; i < 2; ++i)
      b_src[h][i] = (size_t)(1024 + col0 + h * 128 + ((tid + i * 512) >> 3)) * 1024 + ssrc;

  auto stgA = [&](int c, int kt, int buf) {
    gload16(A + a_src[c] + kt * 64, As + buf * 12288 + c * 4096 + tid * 8);
  };
  auto stgB = [&](int h, int kt, int buf) {
    gload16(B + b_src[h][0] + kt * 64, Bs + buf * 16384 + h * 8192 + tid * 8);
    gload16(B + b_src[h][1] + kt * 64, Bs + buf * 16384 + h * 8192 + 4096 + tid * 8);
  };

  const char* As8 = (const char*)As;
  const char* Bs8 = (const char*)Bs;
  const int swz = lane & 7;

  f32x4 acc[6][4];
  #pragma unroll
  for (int f = 0; f < 6; ++f)
    #pragma unroll
    for (int g = 0; g < 4; ++g) acc[f][g] = (f32x4){0.f, 0.f, 0.f, 0.f};

  bf16x8 avA[3], avB[3], bv0[4], bv1[4];

  // prologue: t0 full (7 ops) + t1 B,Ac0 (5 ops); wait t0; pre-issue c(p1)
  stgB(0, 0, 0); stgB(1, 0, 0); stgA(0, 0, 0); stgA(1, 0, 0); stgA(2, 0, 0);
  stgB(0, 1, 1); stgB(1, 1, 1); stgA(0, 1, 1);
  VMC(5); BAR();
  LDA6(avA, 0, 0, 0); LDB4(bv0, 0, 0);

  for (int I = 0; I < 7; ++I) {
    const int kA = 2 * I + 1, kB = 2 * I + 2, kC = 2 * I + 3;
    // p1
    BAR(); stgA(1, kA, 1);
    LDA6(avB, 0, 1, 0); LDB4(bv1, 1, 0);
    LGKM(7); PRIO1; MM6(avA, bv0, 0); PRIO0;
    // p2
    BAR(); stgA(2, kA, 1);
    LDA6(avA, 3, 0, 0);
    LGKM(3); PRIO1; MM6(avB, bv1, 0); PRIO0;
    // p3
    BAR(); stgB(0, kB, 0); VMC(2);
    LDA6(avB, 3, 1, 0);
    LGKM(3); PRIO1; MM6(avA, bv0, 3); PRIO0;
    // p4
    BAR(); stgB(1, kB, 0); stgA(0, kB, 0);
    LDA6(avA, 0, 0, 1); LDB4(bv0, 0, 1);
    LGKM(7); PRIO1; MM6(avB, bv1, 3); PRIO0;
    // p5
    BAR(); stgA(1, kB, 0);
    LDA6(avB, 0, 1, 1); LDB4(bv1, 1, 1);
    LGKM(7); PRIO1; MM6(avA, bv0, 0); PRIO0;
    // p6
    BAR(); stgA(2, kB, 0);
    LDA6(avA, 3, 0, 1);
    LGKM(3); PRIO1; MM6(avB, bv1, 0); PRIO0;
    // p7
    BAR(); stgB(0, kC, 1); VMC(2);
    LDA6(avB, 3, 1, 1);
    LGKM(3); PRIO1; MM6(avA, bv0, 3); PRIO0;
    // p8
    BAR(); stgB(1, kC, 1); stgA(0, kC, 1);
    LDA6(avA, 0, 0, 0); LDB4(bv0, 0, 0);
    LGKM(7); PRIO1; MM6(avB, bv1, 3); PRIO0;
  }

  // peeled final iteration: tiles 14 (b0), 15 (b1); no staging past t15
  {
    BAR(); stgA(1, 15, 1);
    LDA6(avB, 0, 1, 0); LDB4(bv1, 1, 0);
    LGKM(7); PRIO1; MM6(avA, bv0, 0); PRIO0;

    BAR(); stgA(2, 15, 1);
    LDA6(avA, 3, 0, 0);
    LGKM(3); PRIO1; MM6(avB, bv1, 0); PRIO0;

    BAR(); VMC(0);
    LDA6(avB, 3, 1, 0);
    LGKM(3); PRIO1; MM6(avA, bv0, 3); PRIO0;

    BAR();
    LDA6(avA, 0, 0, 1); LDB4(bv0, 0, 1);
    LGKM(7); PRIO1; MM6(avB, bv1, 3); PRIO0;

    BAR();
    LDA6(avB, 0, 1, 1); LDB4(bv1, 1, 1);
    LGKM(7); PRIO1; MM6(avA, bv0, 0); PRIO0;

    BAR();
    LDA6(avA, 3, 0, 1);
    LGKM(3); PRIO1; MM6(avB, bv1, 0); PRIO0;

    BAR();
    LDA6(avB, 3, 1, 1);
    LGKM(3); PRIO1; MM6(avA, bv0, 3); PRIO0;

    BAR();
    LGKM(0); PRIO1; MM6(avB, bv1, 3); PRIO0;
  }

  // epilogue: bf16 C, ldc 2048
  #pragma unroll
  for (int f = 0; f < 6; ++f) {
    #pragma unroll
    for (int j = 0; j < 4; ++j) {
      const int r = row0 + (2 * f + wm) * 16 + lq * 4 + j;
      short* cp = C + (size_t)r * 2048 + col0 + wn * 64 + lr;
      #pragma unroll
      for (int g = 0; g < 4; ++g)
        cp[g * 16] = f2bf(acc[f][g][j]);
    }
  }
}

// ============ 64x128 m97-structure OUT-GEMM (192 blocks, proven r6) =======
__global__ __launch_bounds__(256)
void out_gemm64(const short* __restrict__ A, const short* __restrict__ B,
                float* __restrict__ C,
                const int* __restrict__ f_ids, const int* __restrict__ t_ids,
                const float* __restrict__ bias)
{
  __shared__ __align__(16) short As[4096];    // 64 x 64
  __shared__ __align__(16) short Bs[8192];    // 128 x 64

  const int tid = threadIdx.x;
  const int w = tid >> 6, lane = tid & 63;
  const int row0 = blockIdx.y * 64, col0 = blockIdx.x * 128;
  const int lr = lane & 15, lq = lane >> 4;
  const int wrow = (w >> 1) * 32, wcol = (w & 1) * 64;

  size_t asrc[2]; short* adst[2];
  #pragma unroll
  for (int c = 0; c < 2; ++c) {
    const int d = c * 256 + tid, r = d >> 3;
    const int ss = (d & 7) ^ (r & 7);
    asrc[c] = (size_t)(row0 + r) * 1024 + ss * 8;
    adst[c] = As + d * 8;
  }
  size_t bsrc[4]; short* bdst[4];
  #pragma unroll
  for (int c = 0; c < 4; ++c) {
    const int d = c * 256 + tid, r = d >> 3;
    const int ss = (d & 7) ^ (r & 7);
    bsrc[c] = (size_t)(col0 + r) * 1024 + ss * 8;
    bdst[c] = Bs + d * 8;
  }

  const char* As8 = (const char*)As;
  const char* Bs8 = (const char*)Bs;
  const int swz = lr & 7;

  f32x4 acc[2][4];
  #pragma unroll
  for (int m = 0; m < 2; ++m)
    #pragma unroll
    for (int n = 0; n < 4; ++n) acc[m][n] = (f32x4){0.f, 0.f, 0.f, 0.f};

  for (int kt = 0; kt < 16; ++kt) {
    #pragma unroll
    for (int c = 0; c < 2; ++c) gload16(A + asrc[c] + kt * 64, adst[c]);
    #pragma unroll
    for (int c = 0; c < 4; ++c) gload16(B + bsrc[c] + kt * 64, bdst[c]);
    __syncthreads();
    #pragma unroll
    for (int kk = 0; kk < 2; ++kk) {
      const int so = ((kk * 4 + lq) ^ swz) << 4;
      bf16x8 av[2], bv[4];
      #pragma unroll
      for (int m = 0; m < 2; ++m)
        av[m] = *(const bf16x8*)(As8 + (wrow + m * 16 + lr) * 128 + so);
      #pragma unroll
      for (int n = 0; n < 4; ++n)
        bv[n] = *(const bf16x8*)(Bs8 + (wcol + n * 16 + lr) * 128 + so);
      #pragma unroll
      for (int m = 0; m < 2; ++m)
        #pragma unroll
        for (int n = 0; n < 4; ++n)
          acc[m][n] = __builtin_amdgcn_mfma_f32_16x16x32_bf16(
              av[m], bv[n], acc[m][n], 0, 0, 0);
    }
    __syncthreads();
  }

  float bb[4];
  #pragma unroll
  for (int n = 0; n < 4; ++n) bb[n] = bias[col0 + wcol + n * 16 + lr];
  #pragma unroll
  for (int m = 0; m < 2; ++m)
    #pragma unroll
    for (int j = 0; j < 4; ++j) {
      const int r  = row0 + wrow + m * 16 + lq * 4 + j;
      const int bi = r >= NB;
      const int nn = r - bi * NB;
      const int bf = f_ids[nn], bt = t_ids[nn];
      const int qf = clampi(bf, 0, FG - 1), qi = clampi(bt, 0, L - 1);
      const bool valid = (bf == qf) && (bt == qi);
      const size_t obase = ((size_t)(bi * FG + qf) * L + qi) * 1024;
      #pragma unroll
      for (int n = 0; n < 4; ++n) {
        const int col = col0 + wcol + n * 16 + lr;
        C[obase + col] = valid ? (acc[m][n][j] + bb[n]) : 0.f;
      }
    }
}

// One wave per (bi, n, h). Fuses q/k/v ray rotation, scores, softmax, PV,
// inverse rotation. q fp32 in, kv bf16 in, out bf16 (feeds OUT-GEMM).
__global__ __launch_bounds__(256)
void attn_kernel(const float* __restrict__ dray,
                 const int* __restrict__ bfid, const int* __restrict__ blid,
                 const int* __restrict__ bsid,
                 const int* __restrict__ nfid, const int* __restrict__ ntid,
                 const int* __restrict__ nlid, const int* __restrict__ nsid,
                 const int* __restrict__ nmask,
                 const float* __restrict__ qbuf,
                 const __hip_bfloat16* __restrict__ kvbuf,
                 __hip_bfloat16* __restrict__ obuf)
{
  const int lane = threadIdx.x & 63;
  const int gw   = blockIdx.x * 4 + (threadIdx.x >> 6);
  const int h    = gw & (H - 1);
  const int bn   = gw >> 4;
  const int n    = bn % NB;

  int st = clampi(bsid[n], 0, STAGES - 1);
  int f  = clampi(bfid[n], 0, FG - 1);
  int lc = clampi(blid[n], 0, L - 1);
  const float* dqp = dray + ((size_t)(st * FG + f) * L + lc) * 9;
  float dq[9];
  #pragma unroll
  for (int t = 0; t < 9; ++t) dq[t] = dqp[t];

  const float qraw = qbuf[(size_t)bn * ADIM + h * HD + lane];
  const int rr = lane & 15;

  float x0 = __shfl(qraw, rr), x1 = __shfl(qraw, 16 + rr), x2 = __shfl(qraw, 32 + rr);
  float q0 = dq[0]*x0 + dq[1]*x1 + dq[2]*x2;
  float q1 = dq[3]*x0 + dq[4]*x1 + dq[5]*x2;
  float q2 = dq[6]*x0 + dq[7]*x1 + dq[8]*x2;
  float qd = lane < 16 ? q0 : lane < 32 ? q1 : lane < 48 ? q2 : qraw;

  const __hip_bfloat16* kvb = kvbuf + (size_t)bn * MN * 2048 + h * HD;
  float s[MN], vd[MN];
  #pragma unroll
  for (int m = 0; m < MN; ++m) {
    const int idx = n * MN + m;
    int nst = clampi(nsid[idx], 0, STAGES - 1);
    int nfc = clampi(nfid[idx], 0, FG - 1);
    int nlc = clampi(nlid[idx], 0, L - 1);
    const float* dkp = dray + ((size_t)(nst * FG + nfc) * L + nlc) * 9;
    float dk[9];
    #pragma unroll
    for (int t = 0; t < 9; ++t) dk[t] = dkp[t];

    float kraw = __bfloat162float(kvb[(size_t)m * 2048 + lane]);
    float k0 = __shfl(kraw, rr), k1 = __shfl(kraw, 16 + rr), k2 = __shfl(kraw, 32 + rr);
    float kr0 = dk[0]*k0 + dk[1]*k1 + dk[2]*k2;
    float kr1 = dk[3]*k0 + dk[4]*k1 + dk[5]*k2;
    float kr2 = dk[6]*k0 + dk[7]*k1 + dk[8]*k2;
    float kd = lane < 16 ? kr0 : lane < 32 ? kr1 : lane < 48 ? kr2 : kraw;

    float p = qd * kd;
    #pragma unroll
    for (int off = 32; off; off >>= 1) p += __shfl_xor(p, off);
    s[m] = p;

    float vraw = __bfloat162float(kvb[(size_t)m * 2048 + 1024 + lane]);
    float v0 = __shfl(vraw, rr), v1 = __shfl(vraw, 16 + rr), v2 = __shfl(vraw, 32 + rr);
    float vr0 = dk[0]*v0 + dk[1]*v1 + dk[2]*v2;
    float vr1 = dk[3]*v0 + dk[4]*v1 + dk[5]*v2;
    float vr2 = dk[6]*v0 + dk[7]*v1 + dk[8]*v2;
    vd[m] = lane < 16 ? vr0 : lane < 32 ? vr1 : lane < 48 ? vr2 : vraw;
  }

  float mx = -INFINITY;
  #pragma unroll
  for (int m = 0; m < MN; ++m) {
    const int idx = n * MN + m;
    int nf = nfid[idx], nt = ntid[idx];
    bool ok = (nmask[idx] != 0) && nf >= 0 && nf < FG && nt >= 0 && nt < L;
    s[m] = ok ? s[m] * SCALE : -INFINITY;
    mx = fmaxf(mx, s[m]);
  }
  float den = 0.f;
  #pragma unroll
  for (int m = 0; m < MN; ++m) { s[m] = expf(s[m] - mx); den += s[m]; }
  float inv = 1.0f / den;

  float od = 0.f;
  #pragma unroll
  for (int m = 0; m < MN; ++m) od += s[m] * vd[m];
  od *= inv;

  float y0 = __shfl(od, rr), y1 = __shfl(od, 16 + rr), y2 = __shfl(od, 32 + rr);
  float t0 = dq[0]*y0 + dq[3]*y1 + dq[6]*y2;
  float t1 = dq[1]*y0 + dq[4]*y1 + dq[7]*y2;
  float t2 = dq[2]*y0 + dq[5]*y1 + dq[8]*y2;
  float outd = lane < 16 ? t0 : lane < 32 ? t1 : lane < 48 ? t2 : od;

  obuf[(size_t)bn * ADIM + h * HD + lane] = __float2bfloat16(outd);
}

extern "C" void kernel_launch(void* const* d_in, const int* in_sizes, int n_in,
                              void* d_out, int out_size, void* d_ws, size_t ws_size,
                              hipStream_t stream) {
  const float* x     = (const float*)d_in[0];
  const float* qkv_w = (const float*)d_in[1];
  const float* out_w = (const float*)d_in[2];
  const float* out_b = (const float*)d_in[3];
  const float* dray  = (const float*)d_in[4];
  const int* bfid  = (const int*)d_in[5];
  const int* btid  = (const int*)d_in[6];
  const int* blid  = (const int*)d_in[7];
  const int* bsid  = (const int*)d_in[8];
  const int* nfid  = (const int*)d_in[9];
  const int* ntid  = (const int*)d_in[10];
  const int* nlid  = (const int*)d_in[11];
  const int* nsid  = (const int*)d_in[12];
  const int* nmask = (const int*)d_in[13];

  char* ws = (char*)d_ws;
  short* xb    = (short*)(ws);                  // 12288*1024 bf16 = 25165824 B
  short* qwT   = (short*)(ws + 25165824);       // 3072*1024  bf16 =  6291456 B
  short* owT   = (short*)(ws + 31457280);       // 1024*1024  bf16 =  2097152 B
  float* qbuf  = (float*)(ws + 33554432);       // 1536*1024  f32  =  6291456 B
  short* kvbuf = (short*)(ws + 39845888);       // 12288*2048 bf16 = 50331648 B
  short* obuf  = (short*)(ws + 90177536);       // 1536*1024  bf16 =  3145728 B

  (void)hipMemsetAsync(d_out, 0, (size_t)out_size * sizeof(float), stream);

  conv_bf16<<<6144, 256, 0, stream>>>(x, xb);
  transpose_both<<<dim3(96, 32, 2), 256, 0, stream>>>(qkv_w, qwT, out_w, owT);

  // Q projection: 1536 x 1024 x 1024 (m97 structure, 96 blocks multi/CU)
  q_gemm128<<<dim3(8, 12), 256, 0, stream>>>(xb, qwT, qbuf, bfid, btid);
  // KV projection: 12288 x 2048 x 1024 (192x256 read-ahead, 512 blocks)
  kv_gemm192<<<dim3(8, 64), 512, 0, stream>>>(xb, qwT, kvbuf, nfid, ntid);
  // fused rotations + attention
  attn_kernel<<<6144, 256, 0, stream>>>(dray, bfid, blid, bsid,
                                        nfid, ntid, nlid, nsid, nmask,
                                        qbuf, (const __hip_bfloat16*)kvbuf,
                                        (__hip_bfloat16*)obuf);
  // output projection + bias + valid mask + scatter: 1536 x 1024 x 1024
  out_gemm64<<<dim3(8, 24), 256, 0, stream>>>(obuf, owT, (float*)d_out,
                                              bfid, btid, out_b);
}

// Round 8
// 165.730 us; speedup vs baseline: 1.1155x; 1.0646x over previous
//
#include <hip/hip_runtime.h>
#include <hip/hip_bf16.h>
#include <cstddef>

#define FG 6
#define L 1024
#define NB 768
#define MN 8
#define H 16
#define HD 64
#define ADIM 1024
#define STAGES 4
#define SCALE 0.125f

typedef __attribute__((ext_vector_type(8))) short bf16x8;
typedef __attribute__((ext_vector_type(4))) float f32x4;
typedef __attribute__((address_space(3))) short lds_short_t;
typedef const __attribute__((address_space(1))) short g_short_t;

__device__ __forceinline__ int clampi(int v, int lo, int hi) {
  return v < lo ? lo : (v > hi ? hi : v);
}

__device__ __forceinline__ short f2bf(float f) {
  __hip_bfloat16 h = __float2bfloat16(f);
  return *reinterpret_cast<short*>(&h);
}

__device__ __forceinline__ void gload16(const short* g, short* l) {
  __builtin_amdgcn_global_load_lds((g_short_t*)g, (lds_short_t*)l, 16, 0, 0);
}

// fp32 -> bf16 bulk convert (8 elems/thread)
__global__ __launch_bounds__(256)
void conv_bf16(const float* __restrict__ in, short* __restrict__ out) {
  size_t i = ((size_t)blockIdx.x * 256 + threadIdx.x) * 8;
  float4 a = *(const float4*)(in + i);
  float4 b = *(const float4*)(in + i + 4);
  bf16x8 v;
  v[0] = f2bf(a.x); v[1] = f2bf(a.y); v[2] = f2bf(a.z); v[3] = f2bf(a.w);
  v[4] = f2bf(b.x); v[5] = f2bf(b.y); v[6] = f2bf(b.z); v[7] = f2bf(b.w);
  *(bf16x8*)(out + i) = v;
}

// z=0: qkv_w (1024x3072) -> qwT (3072x1024); z=1 (x<32): out_w -> owT
__global__ __launch_bounds__(256)
void transpose_both(const float* __restrict__ qkv_w, short* __restrict__ qwT,
                    const float* __restrict__ out_w, short* __restrict__ owT) {
  const int z = blockIdx.z;
  if (z == 1 && blockIdx.x >= 32) return;
  const float* in = z ? out_w : qkv_w;
  short* out = z ? owT : qwT;
  const int N = z ? 1024 : 3072;
  __shared__ float tile[32][33];
  const int n0 = blockIdx.x * 32, k0 = blockIdx.y * 32;
  const int tx = threadIdx.x & 31, ty = threadIdx.x >> 5;
  #pragma unroll
  for (int i = 0; i < 4; ++i)
    tile[ty + i * 8][tx] = in[(size_t)(k0 + ty + i * 8) * N + n0 + tx];
  __syncthreads();
  #pragma unroll
  for (int i = 0; i < 4; ++i)
    out[(size_t)(n0 + ty + i * 8) * 1024 + k0 + tx] =
        f2bf(tile[tx][ty + i * 8]);
}

// ============ 64x128 m97-structure Q-GEMM (192 blocks) ====================
// A=xb gathered (bfid,btid), B=qwT[0:1024), C=qbuf fp32 ldc1024
__global__ __launch_bounds__(256)
void q_gemm64(const short* __restrict__ A, const short* __restrict__ B,
              float* __restrict__ C,
              const int* __restrict__ f_ids, const int* __restrict__ t_ids)
{
  __shared__ __align__(16) short As[4096];    // 64 x 64
  __shared__ __align__(16) short Bs[8192];    // 128 x 64

  const int tid = threadIdx.x;
  const int w = tid >> 6, lane = tid & 63;
  const int row0 = blockIdx.y * 64, col0 = blockIdx.x * 128;
  const int lr = lane & 15, lq = lane >> 4;
  const int wrow = (w >> 1) * 32, wcol = (w & 1) * 64;

  size_t asrc[2]; short* adst[2];
  #pragma unroll
  for (int c = 0; c < 2; ++c) {
    const int d = c * 256 + tid, r = d >> 3;
    const int ss = (d & 7) ^ (r & 7);
    const int rr = row0 + r;
    const int bi = rr >= NB;
    const int idx = rr - bi * NB;
    const int f = clampi(f_ids[idx], 0, FG - 1);
    const int q = clampi(t_ids[idx], 0, L - 1);
    asrc[c] = (size_t)((bi * FG + f) * L + q) * 1024 + ss * 8;
    adst[c] = As + d * 8;
  }
  size_t bsrc[4]; short* bdst[4];
  #pragma unroll
  for (int c = 0; c < 4; ++c) {
    const int d = c * 256 + tid, r = d >> 3;
    const int ss = (d & 7) ^ (r & 7);
    bsrc[c] = (size_t)(col0 + r) * 1024 + ss * 8;
    bdst[c] = Bs + d * 8;
  }

  const char* As8 = (const char*)As;
  const char* Bs8 = (const char*)Bs;
  const int swz = lr & 7;

  f32x4 acc[2][4];
  #pragma unroll
  for (int m = 0; m < 2; ++m)
    #pragma unroll
    for (int n = 0; n < 4; ++n) acc[m][n] = (f32x4){0.f, 0.f, 0.f, 0.f};

  for (int kt = 0; kt < 16; ++kt) {
    #pragma unroll
    for (int c = 0; c < 2; ++c) gload16(A + asrc[c] + kt * 64, adst[c]);
    #pragma unroll
    for (int c = 0; c < 4; ++c) gload16(B + bsrc[c] + kt * 64, bdst[c]);
    __syncthreads();
    #pragma unroll
    for (int kk = 0; kk < 2; ++kk) {
      const int so = ((kk * 4 + lq) ^ swz) << 4;
      bf16x8 av[2], bv[4];
      #pragma unroll
      for (int m = 0; m < 2; ++m)
        av[m] = *(const bf16x8*)(As8 + (wrow + m * 16 + lr) * 128 + so);
      #pragma unroll
      for (int n = 0; n < 4; ++n)
        bv[n] = *(const bf16x8*)(Bs8 + (wcol + n * 16 + lr) * 128 + so);
      #pragma unroll
      for (int m = 0; m < 2; ++m)
        #pragma unroll
        for (int n = 0; n < 4; ++n)
          acc[m][n] = __builtin_amdgcn_mfma_f32_16x16x32_bf16(
              av[m], bv[n], acc[m][n], 0, 0, 0);
    }
    __syncthreads();
  }

  #pragma unroll
  for (int m = 0; m < 2; ++m)
    #pragma unroll
    for (int j = 0; j < 4; ++j) {
      const int r = row0 + wrow + m * 16 + lq * 4 + j;
      #pragma unroll
      for (int n = 0; n < 4; ++n)
        C[(size_t)r * 1024 + col0 + wcol + n * 16 + lr] = acc[m][n][j];
    }
}

// ============ 192x256 KV-GEMM, m201 phase discipline ======================
// M=12288 gathered, N=2048 (qkv_w cols 1024..3071), K=1024. Grid 8x64 = 512
// blocks = exactly 2 rounds on 256 CUs (1 block/CU at 112 KiB LDS).
// Per phase (m201 template): {ds_reads for THIS phase's MFMA; staging issue;
// BAR; lgkmcnt(0); setprio1; 12 MFMA; setprio0; [VMC(5) at p4/p8]; BAR}.
// Every staged LDS region is >= 2 barriers after its last reader; VMC(5)
// covers exactly the 5 gloads issued since the guarded tile completed.

#define BAR()   do { __builtin_amdgcn_s_barrier(); __builtin_amdgcn_sched_barrier(0); } while (0)
#define LGKM(N) do { asm volatile("s_waitcnt lgkmcnt(" #N ")" ::: "memory"); __builtin_amdgcn_sched_barrier(0); } while (0)
#define VMC(N)  do { asm volatile("s_waitcnt vmcnt(" #N ")" ::: "memory"); __builtin_amdgcn_sched_barrier(0); } while (0)
#define PRIO1   __builtin_amdgcn_s_setprio(1)
#define PRIO0   __builtin_amdgcn_s_setprio(0)

#define LDA6(D, FB, KK, BUF)                                                  \
  { _Pragma("unroll")                                                         \
    for (int f_ = 0; f_ < 3; ++f_) {                                          \
      const int row_ = (2 * ((FB) + f_) + wm) * 16 + lr;                      \
      D[f_] = *(const bf16x8*)(As8 + (BUF) * 24576 + row_ * 128               \
               + ((((KK) * 4 + lq) ^ swz) << 4));                             \
    } }

#define LDB4(D, KK, BUF)                                                      \
  { _Pragma("unroll")                                                         \
    for (int g_ = 0; g_ < 4; ++g_) {                                          \
      const int row_ = wn * 64 + g_ * 16 + lr;                                \
      D[g_] = *(const bf16x8*)(Bs8 + (BUF) * 32768 + row_ * 128               \
               + ((((KK) * 4 + lq) ^ swz) << 4));                             \
    } }

#define MM6(AV, BV, FB)                                                       \
  { _Pragma("unroll")                                                         \
    for (int f_ = 0; f_ < 3; ++f_)                                            \
      _Pragma("unroll")                                                       \
      for (int g_ = 0; g_ < 4; ++g_)                                          \
        acc[(FB) + f_][g_] = __builtin_amdgcn_mfma_f32_16x16x32_bf16(         \
            AV[f_], BV[g_], acc[(FB) + f_][g_], 0, 0, 0); }

__global__ __launch_bounds__(512, 2)
void kv_gemm192(const short* __restrict__ A, const short* __restrict__ B,
                short* __restrict__ C,
                const int* __restrict__ f_ids, const int* __restrict__ t_ids)
{
  __shared__ __align__(16) short As[24576];   // 2 x 192 x 64 = 48 KiB
  __shared__ __align__(16) short Bs[32768];   // 2 x 256 x 64 = 64 KiB

  const int tid = threadIdx.x;
  const int w = tid >> 6, lane = tid & 63;
  const int wm = w >> 2, wn = w & 3;
  const int lr = lane & 15, lq = lane >> 4;
  const int row0 = blockIdx.y * 192;
  const int col0 = blockIdx.x * 256;

  // inverse-swizzled source offset (elements); same for A chunks & B halves
  const int ssrc = (((tid & 7) ^ ((tid >> 3) & 7))) * 8;

  size_t a_src[3];
  #pragma unroll
  for (int c = 0; c < 3; ++c) {
    const int rr = row0 + c * 64 + (tid >> 3);
    const int bi = rr >= NB * MN;
    const int idx = rr - bi * (NB * MN);
    const int f = clampi(f_ids[idx], 0, FG - 1);
    const int q = clampi(t_ids[idx], 0, L - 1);
    a_src[c] = (size_t)((bi * FG + f) * L + q) * 1024 + ssrc;
  }
  size_t b_src[2][2];
  #pragma unroll
  for (int h = 0; h < 2; ++h)
    #pragma unroll
    for (int i = 0; i < 2; ++i)
      b_src[h][i] = (size_t)(1024 + col0 + h * 128 + ((tid + i * 512) >> 3)) * 1024 + ssrc;

  auto stgA = [&](int c, int kt, int buf) {
    gload16(A + a_src[c] + kt * 64, As + buf * 12288 + c * 4096 + tid * 8);
  };
  auto stgB = [&](int h, int kt, int buf) {
    gload16(B + b_src[h][0] + kt * 64, Bs + buf * 16384 + h * 8192 + tid * 8);
    gload16(B + b_src[h][1] + kt * 64, Bs + buf * 16384 + h * 8192 + 4096 + tid * 8);
  };

  const char* As8 = (const char*)As;
  const char* Bs8 = (const char*)Bs;
  const int swz = lane & 7;

  f32x4 acc[6][4];
  #pragma unroll
  for (int f = 0; f < 6; ++f)
    #pragma unroll
    for (int g = 0; g < 4; ++g) acc[f][g] = (f32x4){0.f, 0.f, 0.f, 0.f};

  bf16x8 avA[3], avB[3], bv0[4], bv1[4];

  // prologue: t0 full (7 ops) + t1 B,Ac0 (5 ops); wait t0 landed
  stgB(0, 0, 0); stgB(1, 0, 0); stgA(0, 0, 0); stgA(1, 0, 0); stgA(2, 0, 0);
  stgB(0, 1, 1); stgB(1, 1, 1); stgA(0, 1, 1);
  VMC(5); BAR();

  for (int I = 0; I < 7; ++I) {
    const int kA = 2 * I + 1, kB = 2 * I + 2, kC = 2 * I + 3;
    // p1
    LDA6(avA, 0, 0, 0); LDB4(bv0, 0, 0); stgA(1, kA, 1);
    BAR(); LGKM(0); PRIO1; MM6(avA, bv0, 0); PRIO0; BAR();
    // p2
    LDA6(avB, 0, 1, 0); LDB4(bv1, 1, 0); stgA(2, kA, 1);
    BAR(); LGKM(0); PRIO1; MM6(avB, bv1, 0); PRIO0; BAR();
    // p3
    LDA6(avA, 3, 0, 0); stgB(0, kB, 0);
    BAR(); LGKM(0); PRIO1; MM6(avA, bv0, 3); PRIO0; BAR();
    // p4  (VMC(5) guards tile kA in buf1, first read at p5)
    LDA6(avB, 3, 1, 0); stgB(1, kB, 0); stgA(0, kB, 0);
    BAR(); LGKM(0); PRIO1; MM6(avB, bv1, 3); PRIO0; VMC(5); BAR();
    // p5
    LDA6(avA, 0, 0, 1); LDB4(bv0, 0, 1); stgA(1, kB, 0);
    BAR(); LGKM(0); PRIO1; MM6(avA, bv0, 0); PRIO0; BAR();
    // p6
    LDA6(avB, 0, 1, 1); LDB4(bv1, 1, 1); stgA(2, kB, 0);
    BAR(); LGKM(0); PRIO1; MM6(avB, bv1, 0); PRIO0; BAR();
    // p7
    LDA6(avA, 3, 0, 1); stgB(0, kC, 1);
    BAR(); LGKM(0); PRIO1; MM6(avA, bv0, 3); PRIO0; BAR();
    // p8  (VMC(5) guards tile kB in buf0, first read at next p1)
    LDA6(avB, 3, 1, 1); stgB(1, kC, 1); stgA(0, kC, 1);
    BAR(); LGKM(0); PRIO1; MM6(avB, bv1, 3); PRIO0; VMC(5); BAR();
  }

  // peeled final iteration: tiles 14 (b0), 15 (b1); no staging past t15
  {
    LDA6(avA, 0, 0, 0); LDB4(bv0, 0, 0); stgA(1, 15, 1);
    BAR(); LGKM(0); PRIO1; MM6(avA, bv0, 0); PRIO0; BAR();

    LDA6(avB, 0, 1, 0); LDB4(bv1, 1, 0); stgA(2, 15, 1);
    BAR(); LGKM(0); PRIO1; MM6(avB, bv1, 0); PRIO0; BAR();

    LDA6(avA, 3, 0, 0);
    BAR(); LGKM(0); PRIO1; MM6(avA, bv0, 3); PRIO0; BAR();

    LDA6(avB, 3, 1, 0);
    BAR(); LGKM(0); PRIO1; MM6(avB, bv1, 3); PRIO0; VMC(0); BAR();

    LDA6(avA, 0, 0, 1); LDB4(bv0, 0, 1);
    BAR(); LGKM(0); PRIO1; MM6(avA, bv0, 0); PRIO0; BAR();

    LDA6(avB, 0, 1, 1); LDB4(bv1, 1, 1);
    BAR(); LGKM(0); PRIO1; MM6(avB, bv1, 0); PRIO0; BAR();

    LDA6(avA, 3, 0, 1);
    BAR(); LGKM(0); PRIO1; MM6(avA, bv0, 3); PRIO0; BAR();

    LDA6(avB, 3, 1, 1);
    BAR(); LGKM(0); PRIO1; MM6(avB, bv1, 3); PRIO0;
  }

  // epilogue: bf16 C, ldc 2048
  #pragma unroll
  for (int f = 0; f < 6; ++f) {
    #pragma unroll
    for (int j = 0; j < 4; ++j) {
      const int r = row0 + (2 * f + wm) * 16 + lq * 4 + j;
      short* cp = C + (size_t)r * 2048 + col0 + wn * 64 + lr;
      #pragma unroll
      for (int g = 0; g < 4; ++g)
        cp[g * 16] = f2bf(acc[f][g][j]);
    }
  }
}

// ============ 64x128 m97-structure OUT-GEMM (192 blocks, proven r6) =======
__global__ __launch_bounds__(256)
void out_gemm64(const short* __restrict__ A, const short* __restrict__ B,
                float* __restrict__ C,
                const int* __restrict__ f_ids, const int* __restrict__ t_ids,
                const float* __restrict__ bias)
{
  __shared__ __align__(16) short As[4096];    // 64 x 64
  __shared__ __align__(16) short Bs[8192];    // 128 x 64

  const int tid = threadIdx.x;
  const int w = tid >> 6, lane = tid & 63;
  const int row0 = blockIdx.y * 64, col0 = blockIdx.x * 128;
  const int lr = lane & 15, lq = lane >> 4;
  const int wrow = (w >> 1) * 32, wcol = (w & 1) * 64;

  size_t asrc[2]; short* adst[2];
  #pragma unroll
  for (int c = 0; c < 2; ++c) {
    const int d = c * 256 + tid, r = d >> 3;
    const int ss = (d & 7) ^ (r & 7);
    asrc[c] = (size_t)(row0 + r) * 1024 + ss * 8;
    adst[c] = As + d * 8;
  }
  size_t bsrc[4]; short* bdst[4];
  #pragma unroll
  for (int c = 0; c < 4; ++c) {
    const int d = c * 256 + tid, r = d >> 3;
    const int ss = (d & 7) ^ (r & 7);
    bsrc[c] = (size_t)(col0 + r) * 1024 + ss * 8;
    bdst[c] = Bs + d * 8;
  }

  const char* As8 = (const char*)As;
  const char* Bs8 = (const char*)Bs;
  const int swz = lr & 7;

  f32x4 acc[2][4];
  #pragma unroll
  for (int m = 0; m < 2; ++m)
    #pragma unroll
    for (int n = 0; n < 4; ++n) acc[m][n] = (f32x4){0.f, 0.f, 0.f, 0.f};

  for (int kt = 0; kt < 16; ++kt) {
    #pragma unroll
    for (int c = 0; c < 2; ++c) gload16(A + asrc[c] + kt * 64, adst[c]);
    #pragma unroll
    for (int c = 0; c < 4; ++c) gload16(B + bsrc[c] + kt * 64, bdst[c]);
    __syncthreads();
    #pragma unroll
    for (int kk = 0; kk < 2; ++kk) {
      const int so = ((kk * 4 + lq) ^ swz) << 4;
      bf16x8 av[2], bv[4];
      #pragma unroll
      for (int m = 0; m < 2; ++m)
        av[m] = *(const bf16x8*)(As8 + (wrow + m * 16 + lr) * 128 + so);
      #pragma unroll
      for (int n = 0; n < 4; ++n)
        bv[n] = *(const bf16x8*)(Bs8 + (wcol + n * 16 + lr) * 128 + so);
      #pragma unroll
      for (int m = 0; m < 2; ++m)
        #pragma unroll
        for (int n = 0; n < 4; ++n)
          acc[m][n] = __builtin_amdgcn_mfma_f32_16x16x32_bf16(
              av[m], bv[n], acc[m][n], 0, 0, 0);
    }
    __syncthreads();
  }

  float bb[4];
  #pragma unroll
  for (int n = 0; n < 4; ++n) bb[n] = bias[col0 + wcol + n * 16 + lr];
  #pragma unroll
  for (int m = 0; m < 2; ++m)
    #pragma unroll
    for (int j = 0; j < 4; ++j) {
      const int r  = row0 + wrow + m * 16 + lq * 4 + j;
      const int bi = r >= NB;
      const int nn = r - bi * NB;
      const int bf = f_ids[nn], bt = t_ids[nn];
      const int qf = clampi(bf, 0, FG - 1), qi = clampi(bt, 0, L - 1);
      const bool valid = (bf == qf) && (bt == qi);
      const size_t obase = ((size_t)(bi * FG + qf) * L + qi) * 1024;
      #pragma unroll
      for (int n = 0; n < 4; ++n) {
        const int col = col0 + wcol + n * 16 + lr;
        C[obase + col] = valid ? (acc[m][n][j] + bb[n]) : 0.f;
      }
    }
}

// One wave per (bi, n, h). Fuses q/k/v ray rotation, scores, softmax, PV,
// inverse rotation. q fp32 in, kv bf16 in, out bf16 (feeds OUT-GEMM).
__global__ __launch_bounds__(256)
void attn_kernel(const float* __restrict__ dray,
                 const int* __restrict__ bfid, const int* __restrict__ blid,
                 const int* __restrict__ bsid,
                 const int* __restrict__ nfid, const int* __restrict__ ntid,
                 const int* __restrict__ nlid, const int* __restrict__ nsid,
                 const int* __restrict__ nmask,
                 const float* __restrict__ qbuf,
                 const __hip_bfloat16* __restrict__ kvbuf,
                 __hip_bfloat16* __restrict__ obuf)
{
  const int lane = threadIdx.x & 63;
  const int gw   = blockIdx.x * 4 + (threadIdx.x >> 6);
  const int h    = gw & (H - 1);
  const int bn   = gw >> 4;
  const int n    = bn % NB;

  int st = clampi(bsid[n], 0, STAGES - 1);
  int f  = clampi(bfid[n], 0, FG - 1);
  int lc = clampi(blid[n], 0, L - 1);
  const float* dqp = dray + ((size_t)(st * FG + f) * L + lc) * 9;
  float dq[9];
  #pragma unroll
  for (int t = 0; t < 9; ++t) dq[t] = dqp[t];

  const float qraw = qbuf[(size_t)bn * ADIM + h * HD + lane];
  const int rr = lane & 15;

  float x0 = __shfl(qraw, rr), x1 = __shfl(qraw, 16 + rr), x2 = __shfl(qraw, 32 + rr);
  float q0 = dq[0]*x0 + dq[1]*x1 + dq[2]*x2;
  float q1 = dq[3]*x0 + dq[4]*x1 + dq[5]*x2;
  float q2 = dq[6]*x0 + dq[7]*x1 + dq[8]*x2;
  float qd = lane < 16 ? q0 : lane < 32 ? q1 : lane < 48 ? q2 : qraw;

  const __hip_bfloat16* kvb = kvbuf + (size_t)bn * MN * 2048 + h * HD;
  float s[MN], vd[MN];
  #pragma unroll
  for (int m = 0; m < MN; ++m) {
    const int idx = n * MN + m;
    int nst = clampi(nsid[idx], 0, STAGES - 1);
    int nfc = clampi(nfid[idx], 0, FG - 1);
    int nlc = clampi(nlid[idx], 0, L - 1);
    const float* dkp = dray + ((size_t)(nst * FG + nfc) * L + nlc) * 9;
    float dk[9];
    #pragma unroll
    for (int t = 0; t < 9; ++t) dk[t] = dkp[t];

    float kraw = __bfloat162float(kvb[(size_t)m * 2048 + lane]);
    float k0 = __shfl(kraw, rr), k1 = __shfl(kraw, 16 + rr), k2 = __shfl(kraw, 32 + rr);
    float kr0 = dk[0]*k0 + dk[1]*k1 + dk[2]*k2;
    float kr1 = dk[3]*k0 + dk[4]*k1 + dk[5]*k2;
    float kr2 = dk[6]*k0 + dk[7]*k1 + dk[8]*k2;
    float kd = lane < 16 ? kr0 : lane < 32 ? kr1 : lane < 48 ? kr2 : kraw;

    float p = qd * kd;
    #pragma unroll
    for (int off = 32; off; off >>= 1) p += __shfl_xor(p, off);
    s[m] = p;

    float vraw = __bfloat162float(kvb[(size_t)m * 2048 + 1024 + lane]);
    float v0 = __shfl(vraw, rr), v1 = __shfl(vraw, 16 + rr), v2 = __shfl(vraw, 32 + rr);
    float vr0 = dk[0]*v0 + dk[1]*v1 + dk[2]*v2;
    float vr1 = dk[3]*v0 + dk[4]*v1 + dk[5]*v2;
    float vr2 = dk[6]*v0 + dk[7]*v1 + dk[8]*v2;
    vd[m] = lane < 16 ? vr0 : lane < 32 ? vr1 : lane < 48 ? vr2 : vraw;
  }

  float mx = -INFINITY;
  #pragma unroll
  for (int m = 0; m < MN; ++m) {
    const int idx = n * MN + m;
    int nf = nfid[idx], nt = ntid[idx];
    bool ok = (nmask[idx] != 0) && nf >= 0 && nf < FG && nt >= 0 && nt < L;
    s[m] = ok ? s[m] * SCALE : -INFINITY;
    mx = fmaxf(mx, s[m]);
  }
  float den = 0.f;
  #pragma unroll
  for (int m = 0; m < MN; ++m) { s[m] = expf(s[m] - mx); den += s[m]; }
  float inv = 1.0f / den;

  float od = 0.f;
  #pragma unroll
  for (int m = 0; m < MN; ++m) od += s[m] * vd[m];
  od *= inv;

  float y0 = __shfl(od, rr), y1 = __shfl(od, 16 + rr), y2 = __shfl(od, 32 + rr);
  float t0 = dq[0]*y0 + dq[3]*y1 + dq[6]*y2;
  float t1 = dq[1]*y0 + dq[4]*y1 + dq[7]*y2;
  float t2 = dq[2]*y0 + dq[5]*y1 + dq[8]*y2;
  float outd = lane < 16 ? t0 : lane < 32 ? t1 : lane < 48 ? t2 : od;

  obuf[(size_t)bn * ADIM + h * HD + lane] = __float2bfloat16(outd);
}

extern "C" void kernel_launch(void* const* d_in, const int* in_sizes, int n_in,
                              void* d_out, int out_size, void* d_ws, size_t ws_size,
                              hipStream_t stream) {
  const float* x     = (const float*)d_in[0];
  const float* qkv_w = (const float*)d_in[1];
  const float* out_w = (const float*)d_in[2];
  const float* out_b = (const float*)d_in[3];
  const float* dray  = (const float*)d_in[4];
  const int* bfid  = (const int*)d_in[5];
  const int* btid  = (const int*)d_in[6];
  const int* blid  = (const int*)d_in[7];
  const int* bsid  = (const int*)d_in[8];
  const int* nfid  = (const int*)d_in[9];
  const int* ntid  = (const int*)d_in[10];
  const int* nlid  = (const int*)d_in[11];
  const int* nsid  = (const int*)d_in[12];
  const int* nmask = (const int*)d_in[13];

  char* ws = (char*)d_ws;
  short* xb    = (short*)(ws);                  // 12288*1024 bf16 = 25165824 B
  short* qwT   = (short*)(ws + 25165824);       // 3072*1024  bf16 =  6291456 B
  short* owT   = (short*)(ws + 31457280);       // 1024*1024  bf16 =  2097152 B
  float* qbuf  = (float*)(ws + 33554432);       // 1536*1024  f32  =  6291456 B
  short* kvbuf = (short*)(ws + 39845888);       // 12288*2048 bf16 = 50331648 B
  short* obuf  = (short*)(ws + 90177536);       // 1536*1024  bf16 =  3145728 B

  (void)hipMemsetAsync(d_out, 0, (size_t)out_size * sizeof(float), stream);

  conv_bf16<<<6144, 256, 0, stream>>>(x, xb);
  transpose_both<<<dim3(96, 32, 2), 256, 0, stream>>>(qkv_w, qwT, out_w, owT);

  // Q projection: 1536 x 1024 x 1024 (64x128 tiles, 192 blocks)
  q_gemm64<<<dim3(8, 24), 256, 0, stream>>>(xb, qwT, qbuf, bfid, btid);
  // KV projection: 12288 x 2048 x 1024 (192x256, m201 discipline, 512 blocks)
  kv_gemm192<<<dim3(8, 64), 512, 0, stream>>>(xb, qwT, kvbuf, nfid, ntid);
  // fused rotations + attention
  attn_kernel<<<6144, 256, 0, stream>>>(dray, bfid, blid, bsid,
                                        nfid, ntid, nlid, nsid, nmask,
                                        qbuf, (const __hip_bfloat16*)kvbuf,
                                        (__hip_bfloat16*)obuf);
  // output projection + bias + valid mask + scatter: 1536 x 1024 x 1024
  out_gemm64<<<dim3(8, 24), 256, 0, stream>>>(obuf, owT, (float*)d_out,
                                              bfid, btid, out_b);
}

// Round 9
// 158.691 us; speedup vs baseline: 1.1650x; 1.0444x over previous
//
#include <hip/hip_runtime.h>
#include <hip/hip_bf16.h>
#include <cstddef>

#define FG 6
#define L 1024
#define NB 768
#define MN 8
#define H 16
#define HD 64
#define ADIM 1024
#define STAGES 4
#define SCALE 0.125f

typedef __attribute__((ext_vector_type(8))) short bf16x8;
typedef __attribute__((ext_vector_type(4))) float f32x4;
typedef __attribute__((address_space(3))) short lds_short_t;
typedef const __attribute__((address_space(1))) short g_short_t;

__device__ __forceinline__ int clampi(int v, int lo, int hi) {
  return v < lo ? lo : (v > hi ? hi : v);
}

__device__ __forceinline__ short f2bf(float f) {
  __hip_bfloat16 h = __float2bfloat16(f);
  return *reinterpret_cast<short*>(&h);
}

__device__ __forceinline__ float bf2f(short s) {
  __hip_bfloat16 h = *reinterpret_cast<__hip_bfloat16*>(&s);
  return __bfloat162float(h);
}

__device__ __forceinline__ void gload16(const short* g, short* l) {
  __builtin_amdgcn_global_load_lds((g_short_t*)g, (lds_short_t*)l, 16, 0, 0);
}

// grid 12288: every block zeros 4KB of d_out; blocks < 6144 also convert
// x fp32 -> xb bf16 (8 elems/thread).
__global__ __launch_bounds__(256)
void prep_kernel(const float* __restrict__ in, short* __restrict__ out,
                 float* __restrict__ zout) {
  const size_t zi = ((size_t)blockIdx.x * 256 + threadIdx.x) * 4;
  *(float4*)(zout + zi) = (float4){0.f, 0.f, 0.f, 0.f};
  if (blockIdx.x >= 6144) return;
  size_t i = ((size_t)blockIdx.x * 256 + threadIdx.x) * 8;
  float4 a = *(const float4*)(in + i);
  float4 b = *(const float4*)(in + i + 4);
  bf16x8 v;
  v[0] = f2bf(a.x); v[1] = f2bf(a.y); v[2] = f2bf(a.z); v[3] = f2bf(a.w);
  v[4] = f2bf(b.x); v[5] = f2bf(b.y); v[6] = f2bf(b.z); v[7] = f2bf(b.w);
  *(bf16x8*)(out + i) = v;
}

// z=0: qkv_w (1024x3072) -> qwT (3072x1024); z=1 (x<32): out_w -> owT
__global__ __launch_bounds__(256)
void transpose_both(const float* __restrict__ qkv_w, short* __restrict__ qwT,
                    const float* __restrict__ out_w, short* __restrict__ owT) {
  const int z = blockIdx.z;
  if (z == 1 && blockIdx.x >= 32) return;
  const float* in = z ? out_w : qkv_w;
  short* out = z ? owT : qwT;
  const int N = z ? 1024 : 3072;
  __shared__ float tile[32][33];
  const int n0 = blockIdx.x * 32, k0 = blockIdx.y * 32;
  const int tx = threadIdx.x & 31, ty = threadIdx.x >> 5;
  #pragma unroll
  for (int i = 0; i < 4; ++i)
    tile[ty + i * 8][tx] = in[(size_t)(k0 + ty + i * 8) * N + n0 + tx];
  __syncthreads();
  #pragma unroll
  for (int i = 0; i < 4; ++i)
    out[(size_t)(n0 + ty + i * 8) * 1024 + k0 + tx] =
        f2bf(tile[tx][ty + i * 8]);
}

// ============ 64x128 m97-structure Q-GEMM (192 blocks, proven r8) =========
__global__ __launch_bounds__(256)
void q_gemm64(const short* __restrict__ A, const short* __restrict__ B,
              float* __restrict__ C,
              const int* __restrict__ f_ids, const int* __restrict__ t_ids)
{
  __shared__ __align__(16) short As[4096];    // 64 x 64
  __shared__ __align__(16) short Bs[8192];    // 128 x 64

  const int tid = threadIdx.x;
  const int w = tid >> 6, lane = tid & 63;
  const int row0 = blockIdx.y * 64, col0 = blockIdx.x * 128;
  const int lr = lane & 15, lq = lane >> 4;
  const int wrow = (w >> 1) * 32, wcol = (w & 1) * 64;

  size_t asrc[2]; short* adst[2];
  #pragma unroll
  for (int c = 0; c < 2; ++c) {
    const int d = c * 256 + tid, r = d >> 3;
    const int ss = (d & 7) ^ (r & 7);
    const int rr = row0 + r;
    const int bi = rr >= NB;
    const int idx = rr - bi * NB;
    const int f = clampi(f_ids[idx], 0, FG - 1);
    const int q = clampi(t_ids[idx], 0, L - 1);
    asrc[c] = (size_t)((bi * FG + f) * L + q) * 1024 + ss * 8;
    adst[c] = As + d * 8;
  }
  size_t bsrc[4]; short* bdst[4];
  #pragma unroll
  for (int c = 0; c < 4; ++c) {
    const int d = c * 256 + tid, r = d >> 3;
    const int ss = (d & 7) ^ (r & 7);
    bsrc[c] = (size_t)(col0 + r) * 1024 + ss * 8;
    bdst[c] = Bs + d * 8;
  }

  const char* As8 = (const char*)As;
  const char* Bs8 = (const char*)Bs;
  const int swz = lr & 7;

  f32x4 acc[2][4];
  #pragma unroll
  for (int m = 0; m < 2; ++m)
    #pragma unroll
    for (int n = 0; n < 4; ++n) acc[m][n] = (f32x4){0.f, 0.f, 0.f, 0.f};

  for (int kt = 0; kt < 16; ++kt) {
    #pragma unroll
    for (int c = 0; c < 2; ++c) gload16(A + asrc[c] + kt * 64, adst[c]);
    #pragma unroll
    for (int c = 0; c < 4; ++c) gload16(B + bsrc[c] + kt * 64, bdst[c]);
    __syncthreads();
    #pragma unroll
    for (int kk = 0; kk < 2; ++kk) {
      const int so = ((kk * 4 + lq) ^ swz) << 4;
      bf16x8 av[2], bv[4];
      #pragma unroll
      for (int m = 0; m < 2; ++m)
        av[m] = *(const bf16x8*)(As8 + (wrow + m * 16 + lr) * 128 + so);
      #pragma unroll
      for (int n = 0; n < 4; ++n)
        bv[n] = *(const bf16x8*)(Bs8 + (wcol + n * 16 + lr) * 128 + so);
      #pragma unroll
      for (int m = 0; m < 2; ++m)
        #pragma unroll
        for (int n = 0; n < 4; ++n)
          acc[m][n] = __builtin_amdgcn_mfma_f32_16x16x32_bf16(
              av[m], bv[n], acc[m][n], 0, 0, 0);
    }
    __syncthreads();
  }

  #pragma unroll
  for (int m = 0; m < 2; ++m)
    #pragma unroll
    for (int j = 0; j < 4; ++j) {
      const int r = row0 + wrow + m * 16 + lq * 4 + j;
      #pragma unroll
      for (int n = 0; n < 4; ++n)
        C[(size_t)r * 1024 + col0 + wcol + n * 16 + lr] = acc[m][n][j];
    }
}

// ============ 192x256 KV-GEMM, m201 phase discipline (proven r8) ==========
#define BAR()   do { __builtin_amdgcn_s_barrier(); __builtin_amdgcn_sched_barrier(0); } while (0)
#define LGKM(N) do { asm volatile("s_waitcnt lgkmcnt(" #N ")" ::: "memory"); __builtin_amdgcn_sched_barrier(0); } while (0)
#define VMC(N)  do { asm volatile("s_waitcnt vmcnt(" #N ")" ::: "memory"); __builtin_amdgcn_sched_barrier(0); } while (0)
#define PRIO1   __builtin_amdgcn_s_setprio(1)
#define PRIO0   __builtin_amdgcn_s_setprio(0)

#define LDA6(D, FB, KK, BUF)                                                  \
  { _Pragma("unroll")                                                         \
    for (int f_ = 0; f_ < 3; ++f_) {                                          \
      const int row_ = (2 * ((FB) + f_) + wm) * 16 + lr;                      \
      D[f_] = *(const bf16x8*)(As8 + (BUF) * 24576 + row_ * 128               \
               + ((((KK) * 4 + lq) ^ swz) << 4));                             \
    } }

#define LDB4(D, KK, BUF)                                                      \
  { _Pragma("unroll")                                                         \
    for (int g_ = 0; g_ < 4; ++g_) {                                          \
      const int row_ = wn * 64 + g_ * 16 + lr;                                \
      D[g_] = *(const bf16x8*)(Bs8 + (BUF) * 32768 + row_ * 128               \
               + ((((KK) * 4 + lq) ^ swz) << 4));                             \
    } }

#define MM6(AV, BV, FB)                                                       \
  { _Pragma("unroll")                                                         \
    for (int f_ = 0; f_ < 3; ++f_)                                            \
      _Pragma("unroll")                                                       \
      for (int g_ = 0; g_ < 4; ++g_)                                          \
        acc[(FB) + f_][g_] = __builtin_amdgcn_mfma_f32_16x16x32_bf16(         \
            AV[f_], BV[g_], acc[(FB) + f_][g_], 0, 0, 0); }

__global__ __launch_bounds__(512, 2)
void kv_gemm192(const short* __restrict__ A, const short* __restrict__ B,
                short* __restrict__ C,
                const int* __restrict__ f_ids, const int* __restrict__ t_ids)
{
  __shared__ __align__(16) short As[24576];   // 2 x 192 x 64 = 48 KiB
  __shared__ __align__(16) short Bs[32768];   // 2 x 256 x 64 = 64 KiB

  const int tid = threadIdx.x;
  const int w = tid >> 6, lane = tid & 63;
  const int wm = w >> 2, wn = w & 3;
  const int lr = lane & 15, lq = lane >> 4;
  const int row0 = blockIdx.y * 192;
  const int col0 = blockIdx.x * 256;

  const int ssrc = (((tid & 7) ^ ((tid >> 3) & 7))) * 8;

  size_t a_src[3];
  #pragma unroll
  for (int c = 0; c < 3; ++c) {
    const int rr = row0 + c * 64 + (tid >> 3);
    const int bi = rr >= NB * MN;
    const int idx = rr - bi * (NB * MN);
    const int f = clampi(f_ids[idx], 0, FG - 1);
    const int q = clampi(t_ids[idx], 0, L - 1);
    a_src[c] = (size_t)((bi * FG + f) * L + q) * 1024 + ssrc;
  }
  size_t b_src[2][2];
  #pragma unroll
  for (int h = 0; h < 2; ++h)
    #pragma unroll
    for (int i = 0; i < 2; ++i)
      b_src[h][i] = (size_t)(1024 + col0 + h * 128 + ((tid + i * 512) >> 3)) * 1024 + ssrc;

  auto stgA = [&](int c, int kt, int buf) {
    gload16(A + a_src[c] + kt * 64, As + buf * 12288 + c * 4096 + tid * 8);
  };
  auto stgB = [&](int h, int kt, int buf) {
    gload16(B + b_src[h][0] + kt * 64, Bs + buf * 16384 + h * 8192 + tid * 8);
    gload16(B + b_src[h][1] + kt * 64, Bs + buf * 16384 + h * 8192 + 4096 + tid * 8);
  };

  const char* As8 = (const char*)As;
  const char* Bs8 = (const char*)Bs;
  const int swz = lane & 7;

  f32x4 acc[6][4];
  #pragma unroll
  for (int f = 0; f < 6; ++f)
    #pragma unroll
    for (int g = 0; g < 4; ++g) acc[f][g] = (f32x4){0.f, 0.f, 0.f, 0.f};

  bf16x8 avA[3], avB[3], bv0[4], bv1[4];

  stgB(0, 0, 0); stgB(1, 0, 0); stgA(0, 0, 0); stgA(1, 0, 0); stgA(2, 0, 0);
  stgB(0, 1, 1); stgB(1, 1, 1); stgA(0, 1, 1);
  VMC(5); BAR();

  for (int I = 0; I < 7; ++I) {
    const int kA = 2 * I + 1, kB = 2 * I + 2, kC = 2 * I + 3;
    LDA6(avA, 0, 0, 0); LDB4(bv0, 0, 0); stgA(1, kA, 1);
    BAR(); LGKM(0); PRIO1; MM6(avA, bv0, 0); PRIO0; BAR();
    LDA6(avB, 0, 1, 0); LDB4(bv1, 1, 0); stgA(2, kA, 1);
    BAR(); LGKM(0); PRIO1; MM6(avB, bv1, 0); PRIO0; BAR();
    LDA6(avA, 3, 0, 0); stgB(0, kB, 0);
    BAR(); LGKM(0); PRIO1; MM6(avA, bv0, 3); PRIO0; BAR();
    LDA6(avB, 3, 1, 0); stgB(1, kB, 0); stgA(0, kB, 0);
    BAR(); LGKM(0); PRIO1; MM6(avB, bv1, 3); PRIO0; VMC(5); BAR();
    LDA6(avA, 0, 0, 1); LDB4(bv0, 0, 1); stgA(1, kB, 0);
    BAR(); LGKM(0); PRIO1; MM6(avA, bv0, 0); PRIO0; BAR();
    LDA6(avB, 0, 1, 1); LDB4(bv1, 1, 1); stgA(2, kB, 0);
    BAR(); LGKM(0); PRIO1; MM6(avB, bv1, 0); PRIO0; BAR();
    LDA6(avA, 3, 0, 1); stgB(0, kC, 1);
    BAR(); LGKM(0); PRIO1; MM6(avA, bv0, 3); PRIO0; BAR();
    LDA6(avB, 3, 1, 1); stgB(1, kC, 1); stgA(0, kC, 1);
    BAR(); LGKM(0); PRIO1; MM6(avB, bv1, 3); PRIO0; VMC(5); BAR();
  }

  {
    LDA6(avA, 0, 0, 0); LDB4(bv0, 0, 0); stgA(1, 15, 1);
    BAR(); LGKM(0); PRIO1; MM6(avA, bv0, 0); PRIO0; BAR();

    LDA6(avB, 0, 1, 0); LDB4(bv1, 1, 0); stgA(2, 15, 1);
    BAR(); LGKM(0); PRIO1; MM6(avB, bv1, 0); PRIO0; BAR();

    LDA6(avA, 3, 0, 0);
    BAR(); LGKM(0); PRIO1; MM6(avA, bv0, 3); PRIO0; BAR();

    LDA6(avB, 3, 1, 0);
    BAR(); LGKM(0); PRIO1; MM6(avB, bv1, 3); PRIO0; VMC(0); BAR();

    LDA6(avA, 0, 0, 1); LDB4(bv0, 0, 1);
    BAR(); LGKM(0); PRIO1; MM6(avA, bv0, 0); PRIO0; BAR();

    LDA6(avB, 0, 1, 1); LDB4(bv1, 1, 1);
    BAR(); LGKM(0); PRIO1; MM6(avB, bv1, 0); PRIO0; BAR();

    LDA6(avA, 3, 0, 1);
    BAR(); LGKM(0); PRIO1; MM6(avA, bv0, 3); PRIO0; BAR();

    LDA6(avB, 3, 1, 1);
    BAR(); LGKM(0); PRIO1; MM6(avB, bv1, 3); PRIO0;
  }

  #pragma unroll
  for (int f = 0; f < 6; ++f) {
    #pragma unroll
    for (int j = 0; j < 4; ++j) {
      const int r = row0 + (2 * f + wm) * 16 + lq * 4 + j;
      short* cp = C + (size_t)r * 2048 + col0 + wn * 64 + lr;
      #pragma unroll
      for (int g = 0; g < 4; ++g)
        cp[g * 16] = f2bf(acc[f][g][j]);
    }
  }
}

// ============ 64x128 m97-structure OUT-GEMM (192 blocks, proven r6) =======
__global__ __launch_bounds__(256)
void out_gemm64(const short* __restrict__ A, const short* __restrict__ B,
                float* __restrict__ C,
                const int* __restrict__ f_ids, const int* __restrict__ t_ids,
                const float* __restrict__ bias)
{
  __shared__ __align__(16) short As[4096];    // 64 x 64
  __shared__ __align__(16) short Bs[8192];    // 128 x 64

  const int tid = threadIdx.x;
  const int w = tid >> 6, lane = tid & 63;
  const int row0 = blockIdx.y * 64, col0 = blockIdx.x * 128;
  const int lr = lane & 15, lq = lane >> 4;
  const int wrow = (w >> 1) * 32, wcol = (w & 1) * 64;

  size_t asrc[2]; short* adst[2];
  #pragma unroll
  for (int c = 0; c < 2; ++c) {
    const int d = c * 256 + tid, r = d >> 3;
    const int ss = (d & 7) ^ (r & 7);
    asrc[c] = (size_t)(row0 + r) * 1024 + ss * 8;
    adst[c] = As + d * 8;
  }
  size_t bsrc[4]; short* bdst[4];
  #pragma unroll
  for (int c = 0; c < 4; ++c) {
    const int d = c * 256 + tid, r = d >> 3;
    const int ss = (d & 7) ^ (r & 7);
    bsrc[c] = (size_t)(col0 + r) * 1024 + ss * 8;
    bdst[c] = Bs + d * 8;
  }

  const char* As8 = (const char*)As;
  const char* Bs8 = (const char*)Bs;
  const int swz = lr & 7;

  f32x4 acc[2][4];
  #pragma unroll
  for (int m = 0; m < 2; ++m)
    #pragma unroll
    for (int n = 0; n < 4; ++n) acc[m][n] = (f32x4){0.f, 0.f, 0.f, 0.f};

  for (int kt = 0; kt < 16; ++kt) {
    #pragma unroll
    for (int c = 0; c < 2; ++c) gload16(A + asrc[c] + kt * 64, adst[c]);
    #pragma unroll
    for (int c = 0; c < 4; ++c) gload16(B + bsrc[c] + kt * 64, bdst[c]);
    __syncthreads();
    #pragma unroll
    for (int kk = 0; kk < 2; ++kk) {
      const int so = ((kk * 4 + lq) ^ swz) << 4;
      bf16x8 av[2], bv[4];
      #pragma unroll
      for (int m = 0; m < 2; ++m)
        av[m] = *(const bf16x8*)(As8 + (wrow + m * 16 + lr) * 128 + so);
      #pragma unroll
      for (int n = 0; n < 4; ++n)
        bv[n] = *(const bf16x8*)(Bs8 + (wcol + n * 16 + lr) * 128 + so);
      #pragma unroll
      for (int m = 0; m < 2; ++m)
        #pragma unroll
        for (int n = 0; n < 4; ++n)
          acc[m][n] = __builtin_amdgcn_mfma_f32_16x16x32_bf16(
              av[m], bv[n], acc[m][n], 0, 0, 0);
    }
    __syncthreads();
  }

  float bb[4];
  #pragma unroll
  for (int n = 0; n < 4; ++n) bb[n] = bias[col0 + wcol + n * 16 + lr];
  #pragma unroll
  for (int m = 0; m < 2; ++m)
    #pragma unroll
    for (int j = 0; j < 4; ++j) {
      const int r  = row0 + wrow + m * 16 + lq * 4 + j;
      const int bi = r >= NB;
      const int nn = r - bi * NB;
      const int bf = f_ids[nn], bt = t_ids[nn];
      const int qf = clampi(bf, 0, FG - 1), qi = clampi(bt, 0, L - 1);
      const bool valid = (bf == qf) && (bt == qi);
      const size_t obase = ((size_t)(bi * FG + qf) * L + qi) * 1024;
      #pragma unroll
      for (int n = 0; n < 4; ++n) {
        const int col = col0 + wcol + n * 16 + lr;
        C[obase + col] = valid ? (acc[m][n][j] + bb[n]) : 0.f;
      }
    }
}

// ============ attention v2: one block per bn, LDS-staged KV + metadata ====
// Block = 256 threads (4 waves), grid = BQ*NB = 1536. Stages the full 32KB
// KV row (8 neighbors x 2048) into LDS once, plus d_q (9), d_k (8x9), mask
// (8) cooperatively. Each wave then runs 4 heads with the proven shuffle
// rotation/softmax math, reading K/V from LDS (2-way bank alias = free).
__global__ __launch_bounds__(256)
void attn_kernel2(const float* __restrict__ dray,
                  const int* __restrict__ bfid, const int* __restrict__ blid,
                  const int* __restrict__ bsid,
                  const int* __restrict__ nfid, const int* __restrict__ ntid,
                  const int* __restrict__ nlid, const int* __restrict__ nsid,
                  const int* __restrict__ nmask,
                  const float* __restrict__ qbuf,
                  const short* __restrict__ kvbuf,
                  __hip_bfloat16* __restrict__ obuf)
{
  __shared__ __align__(16) short kvlds[MN * 2048];   // 32 KiB
  __shared__ float smdq[9];
  __shared__ float smdk[MN][9];
  __shared__ int   smok[MN];

  const int bn   = blockIdx.x;
  const int n    = bn % NB;
  const int tid  = threadIdx.x;
  const int w    = tid >> 6, lane = tid & 63;

  // stage KV row (8 x 16B chunks per thread, wave-uniform base + lane*16)
  const short* kvb = kvbuf + (size_t)bn * MN * 2048;
  #pragma unroll
  for (int j = 0; j < 8; ++j)
    gload16(kvb + (j * 256 + tid) * 8, kvlds + (j * 256 + tid) * 8);

  // metadata
  if (tid < 9) {
    int st = clampi(bsid[n], 0, STAGES - 1);
    int f  = clampi(bfid[n], 0, FG - 1);
    int lc = clampi(blid[n], 0, L - 1);
    smdq[tid] = dray[((size_t)(st * FG + f) * L + lc) * 9 + tid];
  } else if (tid >= 64 && tid < 136) {
    const int t = tid - 64, m = t / 9, j = t - m * 9;
    const int idx = n * MN + m;
    int nst = clampi(nsid[idx], 0, STAGES - 1);
    int nfc = clampi(nfid[idx], 0, FG - 1);
    int nlc = clampi(nlid[idx], 0, L - 1);
    smdk[m][j] = dray[((size_t)(nst * FG + nfc) * L + nlc) * 9 + j];
  } else if (tid >= 192 && tid < 192 + MN) {
    const int m = tid - 192;
    const int idx = n * MN + m;
    int nf = nfid[idx], nt = ntid[idx];
    smok[m] = (nmask[idx] != 0) && nf >= 0 && nf < FG && nt >= 0 && nt < L;
  }
  __syncthreads();   // drains vmcnt for the gload16s too

  float dq[9];
  #pragma unroll
  for (int t = 0; t < 9; ++t) dq[t] = smdq[t];

  const int rr = lane & 15;

  for (int hi = 0; hi < 4; ++hi) {
    const int h = hi * 4 + w;

    const float qraw = qbuf[(size_t)bn * ADIM + h * HD + lane];
    float x0 = __shfl(qraw, rr), x1 = __shfl(qraw, 16 + rr), x2 = __shfl(qraw, 32 + rr);
    float q0 = dq[0]*x0 + dq[1]*x1 + dq[2]*x2;
    float q1 = dq[3]*x0 + dq[4]*x1 + dq[5]*x2;
    float q2 = dq[6]*x0 + dq[7]*x1 + dq[8]*x2;
    float qd = lane < 16 ? q0 : lane < 32 ? q1 : lane < 48 ? q2 : qraw;

    float s[MN], vd[MN];
    #pragma unroll
    for (int m = 0; m < MN; ++m) {
      float dk[9];
      #pragma unroll
      for (int t = 0; t < 9; ++t) dk[t] = smdk[m][t];

      float kraw = bf2f(kvlds[m * 2048 + h * HD + lane]);
      float k0 = __shfl(kraw, rr), k1 = __shfl(kraw, 16 + rr), k2 = __shfl(kraw, 32 + rr);
      float kr0 = dk[0]*k0 + dk[1]*k1 + dk[2]*k2;
      float kr1 = dk[3]*k0 + dk[4]*k1 + dk[5]*k2;
      float kr2 = dk[6]*k0 + dk[7]*k1 + dk[8]*k2;
      float kd = lane < 16 ? kr0 : lane < 32 ? kr1 : lane < 48 ? kr2 : kraw;

      float p = qd * kd;
      #pragma unroll
      for (int off = 32; off; off >>= 1) p += __shfl_xor(p, off);
      s[m] = p;

      float vraw = bf2f(kvlds[m * 2048 + 1024 + h * HD + lane]);
      float v0 = __shfl(vraw, rr), v1 = __shfl(vraw, 16 + rr), v2 = __shfl(vraw, 32 + rr);
      float vr0 = dk[0]*v0 + dk[1]*v1 + dk[2]*v2;
      float vr1 = dk[3]*v0 + dk[4]*v1 + dk[5]*v2;
      float vr2 = dk[6]*v0 + dk[7]*v1 + dk[8]*v2;
      vd[m] = lane < 16 ? vr0 : lane < 32 ? vr1 : lane < 48 ? vr2 : vraw;
    }

    float mx = -INFINITY;
    #pragma unroll
    for (int m = 0; m < MN; ++m) {
      s[m] = smok[m] ? s[m] * SCALE : -INFINITY;
      mx = fmaxf(mx, s[m]);
    }
    float den = 0.f;
    #pragma unroll
    for (int m = 0; m < MN; ++m) { s[m] = expf(s[m] - mx); den += s[m]; }
    float inv = 1.0f / den;

    float od = 0.f;
    #pragma unroll
    for (int m = 0; m < MN; ++m) od += s[m] * vd[m];
    od *= inv;

    float y0 = __shfl(od, rr), y1 = __shfl(od, 16 + rr), y2 = __shfl(od, 32 + rr);
    float t0 = dq[0]*y0 + dq[3]*y1 + dq[6]*y2;
    float t1 = dq[1]*y0 + dq[4]*y1 + dq[7]*y2;
    float t2 = dq[2]*y0 + dq[5]*y1 + dq[8]*y2;
    float outd = lane < 16 ? t0 : lane < 32 ? t1 : lane < 48 ? t2 : od;

    obuf[(size_t)bn * ADIM + h * HD + lane] = __float2bfloat16(outd);
  }
}

extern "C" void kernel_launch(void* const* d_in, const int* in_sizes, int n_in,
                              void* d_out, int out_size, void* d_ws, size_t ws_size,
                              hipStream_t stream) {
  const float* x     = (const float*)d_in[0];
  const float* qkv_w = (const float*)d_in[1];
  const float* out_w = (const float*)d_in[2];
  const float* out_b = (const float*)d_in[3];
  const float* dray  = (const float*)d_in[4];
  const int* bfid  = (const int*)d_in[5];
  const int* btid  = (const int*)d_in[6];
  const int* blid  = (const int*)d_in[7];
  const int* bsid  = (const int*)d_in[8];
  const int* nfid  = (const int*)d_in[9];
  const int* ntid  = (const int*)d_in[10];
  const int* nlid  = (const int*)d_in[11];
  const int* nsid  = (const int*)d_in[12];
  const int* nmask = (const int*)d_in[13];

  char* ws = (char*)d_ws;
  short* xb    = (short*)(ws);                  // 12288*1024 bf16 = 25165824 B
  short* qwT   = (short*)(ws + 25165824);       // 3072*1024  bf16 =  6291456 B
  short* owT   = (short*)(ws + 31457280);       // 1024*1024  bf16 =  2097152 B
  float* qbuf  = (float*)(ws + 33554432);       // 1536*1024  f32  =  6291456 B
  short* kvbuf = (short*)(ws + 39845888);       // 12288*2048 bf16 = 50331648 B
  short* obuf  = (short*)(ws + 90177536);       // 1536*1024  bf16 =  3145728 B

  // zero d_out + convert x -> bf16 in one dispatch
  prep_kernel<<<12288, 256, 0, stream>>>(x, xb, (float*)d_out);
  transpose_both<<<dim3(96, 32, 2), 256, 0, stream>>>(qkv_w, qwT, out_w, owT);

  // Q projection: 1536 x 1024 x 1024 (64x128 tiles, 192 blocks)
  q_gemm64<<<dim3(8, 24), 256, 0, stream>>>(xb, qwT, qbuf, bfid, btid);
  // KV projection: 12288 x 2048 x 1024 (192x256, m201 discipline, 512 blocks)
  kv_gemm192<<<dim3(8, 64), 512, 0, stream>>>(xb, qwT, kvbuf, nfid, ntid);
  // fused rotations + attention (one block per bn, LDS-staged)
  attn_kernel2<<<1536, 256, 0, stream>>>(dray, bfid, blid, bsid,
                                         nfid, ntid, nlid, nsid, nmask,
                                         qbuf, kvbuf,
                                         (__hip_bfloat16*)obuf);
  // output projection + bias + valid mask + scatter: 1536 x 1024 x 1024
  out_gemm64<<<dim3(8, 24), 256, 0, stream>>>(obuf, owT, (float*)d_out,
                                              bfid, btid, out_b);
}

// Round 10
// 154.807 us; speedup vs baseline: 1.1942x; 1.0251x over previous
//
#include <hip/hip_runtime.h>
#include <hip/hip_bf16.h>
#include <cstddef>

#define FG 6
#define L 1024
#define NB 768
#define MN 8
#define H 16
#define HD 64
#define ADIM 1024
#define STAGES 4
#define SCALE 0.125f

typedef __attribute__((ext_vector_type(8))) short bf16x8;
typedef __attribute__((ext_vector_type(4))) float f32x4;
typedef __attribute__((address_space(3))) short lds_short_t;
typedef const __attribute__((address_space(1))) short g_short_t;

__device__ __forceinline__ int clampi(int v, int lo, int hi) {
  return v < lo ? lo : (v > hi ? hi : v);
}

__device__ __forceinline__ short f2bf(float f) {
  __hip_bfloat16 h = __float2bfloat16(f);
  return *reinterpret_cast<short*>(&h);
}

__device__ __forceinline__ float bf2f(short s) {
  __hip_bfloat16 h = *reinterpret_cast<__hip_bfloat16*>(&s);
  return __bfloat162float(h);
}

__device__ __forceinline__ void gload16(const short* g, short* l) {
  __builtin_amdgcn_global_load_lds((g_short_t*)g, (lds_short_t*)l, 16, 0, 0);
}

// One dispatch: blocks [0,12288) zero d_out (blocks <6144 also convert x to
// bf16); blocks [12288,15360) transpose qkv_w; [15360,16384) transpose out_w.
__global__ __launch_bounds__(256)
void prep_kernel(const float* __restrict__ x, short* __restrict__ xb,
                 float* __restrict__ zout,
                 const float* __restrict__ qkv_w, short* __restrict__ qwT,
                 const float* __restrict__ out_w, short* __restrict__ owT) {
  const int b = blockIdx.x;
  if (b < 12288) {
    const size_t zi = ((size_t)b * 256 + threadIdx.x) * 4;
    *(float4*)(zout + zi) = (float4){0.f, 0.f, 0.f, 0.f};
    if (b >= 6144) return;
    size_t i = ((size_t)b * 256 + threadIdx.x) * 8;
    float4 a = *(const float4*)(x + i);
    float4 c = *(const float4*)(x + i + 4);
    bf16x8 v;
    v[0] = f2bf(a.x); v[1] = f2bf(a.y); v[2] = f2bf(a.z); v[3] = f2bf(a.w);
    v[4] = f2bf(c.x); v[5] = f2bf(c.y); v[6] = f2bf(c.z); v[7] = f2bf(c.w);
    *(bf16x8*)(xb + i) = v;
    return;
  }
  int t = b - 12288;
  const float* in; short* out; int N, n0, k0;
  if (t < 3072) { in = qkv_w; out = qwT; N = 3072; n0 = (t % 96) * 32; k0 = (t / 96) * 32; }
  else { t -= 3072; in = out_w; out = owT; N = 1024; n0 = (t % 32) * 32; k0 = (t / 32) * 32; }
  __shared__ float tile[32][33];
  const int tx = threadIdx.x & 31, ty = threadIdx.x >> 5;
  #pragma unroll
  for (int i = 0; i < 4; ++i)
    tile[ty + i * 8][tx] = in[(size_t)(k0 + ty + i * 8) * N + n0 + tx];
  __syncthreads();
  #pragma unroll
  for (int i = 0; i < 4; ++i)
    out[(size_t)(n0 + ty + i * 8) * 1024 + k0 + tx] =
        f2bf(tile[tx][ty + i * 8]);
}

// ============ 64x128 m97-structure Q-GEMM (192 blocks, proven r8) =========
__global__ __launch_bounds__(256)
void q_gemm64(const short* __restrict__ A, const short* __restrict__ B,
              float* __restrict__ C,
              const int* __restrict__ f_ids, const int* __restrict__ t_ids)
{
  __shared__ __align__(16) short As[4096];    // 64 x 64
  __shared__ __align__(16) short Bs[8192];    // 128 x 64

  const int tid = threadIdx.x;
  const int w = tid >> 6, lane = tid & 63;
  const int row0 = blockIdx.y * 64, col0 = blockIdx.x * 128;
  const int lr = lane & 15, lq = lane >> 4;
  const int wrow = (w >> 1) * 32, wcol = (w & 1) * 64;

  size_t asrc[2]; short* adst[2];
  #pragma unroll
  for (int c = 0; c < 2; ++c) {
    const int d = c * 256 + tid, r = d >> 3;
    const int ss = (d & 7) ^ (r & 7);
    const int rr = row0 + r;
    const int bi = rr >= NB;
    const int idx = rr - bi * NB;
    const int f = clampi(f_ids[idx], 0, FG - 1);
    const int q = clampi(t_ids[idx], 0, L - 1);
    asrc[c] = (size_t)((bi * FG + f) * L + q) * 1024 + ss * 8;
    adst[c] = As + d * 8;
  }
  size_t bsrc[4]; short* bdst[4];
  #pragma unroll
  for (int c = 0; c < 4; ++c) {
    const int d = c * 256 + tid, r = d >> 3;
    const int ss = (d & 7) ^ (r & 7);
    bsrc[c] = (size_t)(col0 + r) * 1024 + ss * 8;
    bdst[c] = Bs + d * 8;
  }

  const char* As8 = (const char*)As;
  const char* Bs8 = (const char*)Bs;
  const int swz = lr & 7;

  f32x4 acc[2][4];
  #pragma unroll
  for (int m = 0; m < 2; ++m)
    #pragma unroll
    for (int n = 0; n < 4; ++n) acc[m][n] = (f32x4){0.f, 0.f, 0.f, 0.f};

  for (int kt = 0; kt < 16; ++kt) {
    #pragma unroll
    for (int c = 0; c < 2; ++c) gload16(A + asrc[c] + kt * 64, adst[c]);
    #pragma unroll
    for (int c = 0; c < 4; ++c) gload16(B + bsrc[c] + kt * 64, bdst[c]);
    __syncthreads();
    #pragma unroll
    for (int kk = 0; kk < 2; ++kk) {
      const int so = ((kk * 4 + lq) ^ swz) << 4;
      bf16x8 av[2], bv[4];
      #pragma unroll
      for (int m = 0; m < 2; ++m)
        av[m] = *(const bf16x8*)(As8 + (wrow + m * 16 + lr) * 128 + so);
      #pragma unroll
      for (int n = 0; n < 4; ++n)
        bv[n] = *(const bf16x8*)(Bs8 + (wcol + n * 16 + lr) * 128 + so);
      #pragma unroll
      for (int m = 0; m < 2; ++m)
        #pragma unroll
        for (int n = 0; n < 4; ++n)
          acc[m][n] = __builtin_amdgcn_mfma_f32_16x16x32_bf16(
              av[m], bv[n], acc[m][n], 0, 0, 0);
    }
    __syncthreads();
  }

  #pragma unroll
  for (int m = 0; m < 2; ++m)
    #pragma unroll
    for (int j = 0; j < 4; ++j) {
      const int r = row0 + wrow + m * 16 + lq * 4 + j;
      #pragma unroll
      for (int n = 0; n < 4; ++n)
        C[(size_t)r * 1024 + col0 + wcol + n * 16 + lr] = acc[m][n][j];
    }
}

// ============ 192x256 KV-GEMM, 4 fat phases per 2 K-tiles =================
// Same tile/layout/staging/swizzle as r8 (proven); phase count halved to
// amortize the ~385-cyc/phase barrier+drain overhead. Region-safety and
// vmcnt ledger re-audited (see analysis): every staged write issues after a
// barrier following its region's last drained read; VMC(5) at F2/F4 leaves
// exactly the newest 5 gloads outstanding.

#define BAR()   do { __builtin_amdgcn_s_barrier(); __builtin_amdgcn_sched_barrier(0); } while (0)
#define LGKM(N) do { asm volatile("s_waitcnt lgkmcnt(" #N ")" ::: "memory"); __builtin_amdgcn_sched_barrier(0); } while (0)
#define VMC(N)  do { asm volatile("s_waitcnt vmcnt(" #N ")" ::: "memory"); __builtin_amdgcn_sched_barrier(0); } while (0)
#define PRIO1   __builtin_amdgcn_s_setprio(1)
#define PRIO0   __builtin_amdgcn_s_setprio(0)

#define LDA6(D, FB, KK, BUF)                                                  \
  { _Pragma("unroll")                                                         \
    for (int f_ = 0; f_ < 3; ++f_) {                                          \
      const int row_ = (2 * ((FB) + f_) + wm) * 16 + lr;                      \
      D[f_] = *(const bf16x8*)(As8 + (BUF) * 24576 + row_ * 128               \
               + ((((KK) * 4 + lq) ^ swz) << 4));                             \
    } }

#define LDB4(D, KK, BUF)                                                      \
  { _Pragma("unroll")                                                         \
    for (int g_ = 0; g_ < 4; ++g_) {                                          \
      const int row_ = wn * 64 + g_ * 16 + lr;                                \
      D[g_] = *(const bf16x8*)(Bs8 + (BUF) * 32768 + row_ * 128               \
               + ((((KK) * 4 + lq) ^ swz) << 4));                             \
    } }

#define MM6(AV, BV, FB)                                                       \
  { _Pragma("unroll")                                                         \
    for (int f_ = 0; f_ < 3; ++f_)                                            \
      _Pragma("unroll")                                                       \
      for (int g_ = 0; g_ < 4; ++g_)                                          \
        acc[(FB) + f_][g_] = __builtin_amdgcn_mfma_f32_16x16x32_bf16(         \
            AV[f_], BV[g_], acc[(FB) + f_][g_], 0, 0, 0); }

__global__ __launch_bounds__(512, 2)
void kv_gemm192(const short* __restrict__ A, const short* __restrict__ B,
                short* __restrict__ C,
                const int* __restrict__ f_ids, const int* __restrict__ t_ids)
{
  __shared__ __align__(16) short As[24576];   // 2 x 192 x 64 = 48 KiB
  __shared__ __align__(16) short Bs[32768];   // 2 x 256 x 64 = 64 KiB

  const int tid = threadIdx.x;
  const int w = tid >> 6, lane = tid & 63;
  const int wm = w >> 2, wn = w & 3;
  const int lr = lane & 15, lq = lane >> 4;
  const int row0 = blockIdx.y * 192;
  const int col0 = blockIdx.x * 256;

  const int ssrc = (((tid & 7) ^ ((tid >> 3) & 7))) * 8;

  size_t a_src[3];
  #pragma unroll
  for (int c = 0; c < 3; ++c) {
    const int rr = row0 + c * 64 + (tid >> 3);
    const int bi = rr >= NB * MN;
    const int idx = rr - bi * (NB * MN);
    const int f = clampi(f_ids[idx], 0, FG - 1);
    const int q = clampi(t_ids[idx], 0, L - 1);
    a_src[c] = (size_t)((bi * FG + f) * L + q) * 1024 + ssrc;
  }
  size_t b_src[2][2];
  #pragma unroll
  for (int h = 0; h < 2; ++h)
    #pragma unroll
    for (int i = 0; i < 2; ++i)
      b_src[h][i] = (size_t)(1024 + col0 + h * 128 + ((tid + i * 512) >> 3)) * 1024 + ssrc;

  auto stgA = [&](int c, int kt, int buf) {
    gload16(A + a_src[c] + kt * 64, As + buf * 12288 + c * 4096 + tid * 8);
  };
  auto stgB = [&](int h, int kt, int buf) {
    gload16(B + b_src[h][0] + kt * 64, Bs + buf * 16384 + h * 8192 + tid * 8);
    gload16(B + b_src[h][1] + kt * 64, Bs + buf * 16384 + h * 8192 + 4096 + tid * 8);
  };

  const char* As8 = (const char*)As;
  const char* Bs8 = (const char*)Bs;
  const int swz = lane & 7;

  f32x4 acc[6][4];
  #pragma unroll
  for (int f = 0; f < 6; ++f)
    #pragma unroll
    for (int g = 0; g < 4; ++g) acc[f][g] = (f32x4){0.f, 0.f, 0.f, 0.f};

  bf16x8 avA[3], avB[3], bv0[4], bv1[4];

  // prologue: t0 full (7 ops) + t1 B,Ac0 (5 ops); wait t0 landed
  stgB(0, 0, 0); stgB(1, 0, 0); stgA(0, 0, 0); stgA(1, 0, 0); stgA(2, 0, 0);
  stgB(0, 1, 1); stgB(1, 1, 1); stgA(0, 1, 1);
  VMC(5); BAR();

  for (int I = 0; I < 7; ++I) {
    const int kA = 2 * I + 1, kB = 2 * I + 2, kC = 2 * I + 3;
    // F1: buf0 FB0, both kk (14 reads, 24 MFMA); stage A1,A2 of kA -> buf1
    LDA6(avA, 0, 0, 0); LDB4(bv0, 0, 0); LDA6(avB, 0, 1, 0); LDB4(bv1, 1, 0);
    stgA(1, kA, 1); stgA(2, kA, 1);
    BAR(); LGKM(0); PRIO1; MM6(avA, bv0, 0); MM6(avB, bv1, 0); PRIO0; BAR();
    // F2: buf0 FB3 (6 reads, 24 MFMA); stage B+A0 of kB -> buf0
    LDA6(avA, 3, 0, 0); LDA6(avB, 3, 1, 0);
    stgB(0, kB, 0); stgB(1, kB, 0); stgA(0, kB, 0);
    BAR(); LGKM(0); PRIO1; MM6(avA, bv0, 3); MM6(avB, bv1, 3); PRIO0; VMC(5); BAR();
    // F3: buf1 FB0; stage A1,A2 of kB -> buf0
    LDA6(avA, 0, 0, 1); LDB4(bv0, 0, 1); LDA6(avB, 0, 1, 1); LDB4(bv1, 1, 1);
    stgA(1, kB, 0); stgA(2, kB, 0);
    BAR(); LGKM(0); PRIO1; MM6(avA, bv0, 0); MM6(avB, bv1, 0); PRIO0; BAR();
    // F4: buf1 FB3; stage B+A0 of kC -> buf1
    LDA6(avA, 3, 0, 1); LDA6(avB, 3, 1, 1);
    stgB(0, kC, 1); stgB(1, kC, 1); stgA(0, kC, 1);
    BAR(); LGKM(0); PRIO1; MM6(avA, bv0, 3); MM6(avB, bv1, 3); PRIO0; VMC(5); BAR();
  }

  // peeled final iteration: tiles 14 (buf0), 15 (buf1)
  {
    LDA6(avA, 0, 0, 0); LDB4(bv0, 0, 0); LDA6(avB, 0, 1, 0); LDB4(bv1, 1, 0);
    stgA(1, 15, 1); stgA(2, 15, 1);
    BAR(); LGKM(0); PRIO1; MM6(avA, bv0, 0); MM6(avB, bv1, 0); PRIO0; BAR();

    LDA6(avA, 3, 0, 0); LDA6(avB, 3, 1, 0);
    BAR(); LGKM(0); PRIO1; MM6(avA, bv0, 3); MM6(avB, bv1, 3); PRIO0; VMC(0); BAR();

    LDA6(avA, 0, 0, 1); LDB4(bv0, 0, 1); LDA6(avB, 0, 1, 1); LDB4(bv1, 1, 1);
    BAR(); LGKM(0); PRIO1; MM6(avA, bv0, 0); MM6(avB, bv1, 0); PRIO0; BAR();

    LDA6(avA, 3, 0, 1); LDA6(avB, 3, 1, 1);
    BAR(); LGKM(0); PRIO1; MM6(avA, bv0, 3); MM6(avB, bv1, 3); PRIO0;
  }

  // epilogue: bf16 C, ldc 2048
  #pragma unroll
  for (int f = 0; f < 6; ++f) {
    #pragma unroll
    for (int j = 0; j < 4; ++j) {
      const int r = row0 + (2 * f + wm) * 16 + lq * 4 + j;
      short* cp = C + (size_t)r * 2048 + col0 + wn * 64 + lr;
      #pragma unroll
      for (int g = 0; g < 4; ++g)
        cp[g * 16] = f2bf(acc[f][g][j]);
    }
  }
}

// ============ 64x128 m97-structure OUT-GEMM (192 blocks, proven r6) =======
__global__ __launch_bounds__(256)
void out_gemm64(const short* __restrict__ A, const short* __restrict__ B,
                float* __restrict__ C,
                const int* __restrict__ f_ids, const int* __restrict__ t_ids,
                const float* __restrict__ bias)
{
  __shared__ __align__(16) short As[4096];    // 64 x 64
  __shared__ __align__(16) short Bs[8192];    // 128 x 64

  const int tid = threadIdx.x;
  const int w = tid >> 6, lane = tid & 63;
  const int row0 = blockIdx.y * 64, col0 = blockIdx.x * 128;
  const int lr = lane & 15, lq = lane >> 4;
  const int wrow = (w >> 1) * 32, wcol = (w & 1) * 64;

  size_t asrc[2]; short* adst[2];
  #pragma unroll
  for (int c = 0; c < 2; ++c) {
    const int d = c * 256 + tid, r = d >> 3;
    const int ss = (d & 7) ^ (r & 7);
    asrc[c] = (size_t)(row0 + r) * 1024 + ss * 8;
    adst[c] = As + d * 8;
  }
  size_t bsrc[4]; short* bdst[4];
  #pragma unroll
  for (int c = 0; c < 4; ++c) {
    const int d = c * 256 + tid, r = d >> 3;
    const int ss = (d & 7) ^ (r & 7);
    bsrc[c] = (size_t)(col0 + r) * 1024 + ss * 8;
    bdst[c] = Bs + d * 8;
  }

  const char* As8 = (const char*)As;
  const char* Bs8 = (const char*)Bs;
  const int swz = lr & 7;

  f32x4 acc[2][4];
  #pragma unroll
  for (int m = 0; m < 2; ++m)
    #pragma unroll
    for (int n = 0; n < 4; ++n) acc[m][n] = (f32x4){0.f, 0.f, 0.f, 0.f};

  for (int kt = 0; kt < 16; ++kt) {
    #pragma unroll
    for (int c = 0; c < 2; ++c) gload16(A + asrc[c] + kt * 64, adst[c]);
    #pragma unroll
    for (int c = 0; c < 4; ++c) gload16(B + bsrc[c] + kt * 64, bdst[c]);
    __syncthreads();
    #pragma unroll
    for (int kk = 0; kk < 2; ++kk) {
      const int so = ((kk * 4 + lq) ^ swz) << 4;
      bf16x8 av[2], bv[4];
      #pragma unroll
      for (int m = 0; m < 2; ++m)
        av[m] = *(const bf16x8*)(As8 + (wrow + m * 16 + lr) * 128 + so);
      #pragma unroll
      for (int n = 0; n < 4; ++n)
        bv[n] = *(const bf16x8*)(Bs8 + (wcol + n * 16 + lr) * 128 + so);
      #pragma unroll
      for (int m = 0; m < 2; ++m)
        #pragma unroll
        for (int n = 0; n < 4; ++n)
          acc[m][n] = __builtin_amdgcn_mfma_f32_16x16x32_bf16(
              av[m], bv[n], acc[m][n], 0, 0, 0);
    }
    __syncthreads();
  }

  float bb[4];
  #pragma unroll
  for (int n = 0; n < 4; ++n) bb[n] = bias[col0 + wcol + n * 16 + lr];
  #pragma unroll
  for (int m = 0; m < 2; ++m)
    #pragma unroll
    for (int j = 0; j < 4; ++j) {
      const int r  = row0 + wrow + m * 16 + lq * 4 + j;
      const int bi = r >= NB;
      const int nn = r - bi * NB;
      const int bf = f_ids[nn], bt = t_ids[nn];
      const int qf = clampi(bf, 0, FG - 1), qi = clampi(bt, 0, L - 1);
      const bool valid = (bf == qf) && (bt == qi);
      const size_t obase = ((size_t)(bi * FG + qf) * L + qi) * 1024;
      #pragma unroll
      for (int n = 0; n < 4; ++n) {
        const int col = col0 + wcol + n * 16 + lr;
        C[obase + col] = valid ? (acc[m][n][j] + bb[n]) : 0.f;
      }
    }
}

// ============ attention v2 (proven r9): one block per bn ==================
__global__ __launch_bounds__(256)
void attn_kernel2(const float* __restrict__ dray,
                  const int* __restrict__ bfid, const int* __restrict__ blid,
                  const int* __restrict__ bsid,
                  const int* __restrict__ nfid, const int* __restrict__ ntid,
                  const int* __restrict__ nlid, const int* __restrict__ nsid,
                  const int* __restrict__ nmask,
                  const float* __restrict__ qbuf,
                  const short* __restrict__ kvbuf,
                  __hip_bfloat16* __restrict__ obuf)
{
  __shared__ __align__(16) short kvlds[MN * 2048];   // 32 KiB
  __shared__ float smdq[9];
  __shared__ float smdk[MN][9];
  __shared__ int   smok[MN];

  const int bn   = blockIdx.x;
  const int n    = bn % NB;
  const int tid  = threadIdx.x;
  const int w    = tid >> 6, lane = tid & 63;

  const short* kvb = kvbuf + (size_t)bn * MN * 2048;
  #pragma unroll
  for (int j = 0; j < 8; ++j)
    gload16(kvb + (j * 256 + tid) * 8, kvlds + (j * 256 + tid) * 8);

  if (tid < 9) {
    int st = clampi(bsid[n], 0, STAGES - 1);
    int f  = clampi(bfid[n], 0, FG - 1);
    int lc = clampi(blid[n], 0, L - 1);
    smdq[tid] = dray[((size_t)(st * FG + f) * L + lc) * 9 + tid];
  } else if (tid >= 64 && tid < 136) {
    const int t = tid - 64, m = t / 9, j = t - m * 9;
    const int idx = n * MN + m;
    int nst = clampi(nsid[idx], 0, STAGES - 1);
    int nfc = clampi(nfid[idx], 0, FG - 1);
    int nlc = clampi(nlid[idx], 0, L - 1);
    smdk[m][j] = dray[((size_t)(nst * FG + nfc) * L + nlc) * 9 + j];
  } else if (tid >= 192 && tid < 192 + MN) {
    const int m = tid - 192;
    const int idx = n * MN + m;
    int nf = nfid[idx], nt = ntid[idx];
    smok[m] = (nmask[idx] != 0) && nf >= 0 && nf < FG && nt >= 0 && nt < L;
  }
  __syncthreads();

  float dq[9];
  #pragma unroll
  for (int t = 0; t < 9; ++t) dq[t] = smdq[t];

  const int rr = lane & 15;

  for (int hi = 0; hi < 4; ++hi) {
    const int h = hi * 4 + w;

    const float qraw = qbuf[(size_t)bn * ADIM + h * HD + lane];
    float x0 = __shfl(qraw, rr), x1 = __shfl(qraw, 16 + rr), x2 = __shfl(qraw, 32 + rr);
    float q0 = dq[0]*x0 + dq[1]*x1 + dq[2]*x2;
    float q1 = dq[3]*x0 + dq[4]*x1 + dq[5]*x2;
    float q2 = dq[6]*x0 + dq[7]*x1 + dq[8]*x2;
    float qd = lane < 16 ? q0 : lane < 32 ? q1 : lane < 48 ? q2 : qraw;

    float s[MN], vd[MN];
    #pragma unroll
    for (int m = 0; m < MN; ++m) {
      float dk[9];
      #pragma unroll
      for (int t = 0; t < 9; ++t) dk[t] = smdk[m][t];

      float kraw = bf2f(kvlds[m * 2048 + h * HD + lane]);
      float k0 = __shfl(kraw, rr), k1 = __shfl(kraw, 16 + rr), k2 = __shfl(kraw, 32 + rr);
      float kr0 = dk[0]*k0 + dk[1]*k1 + dk[2]*k2;
      float kr1 = dk[3]*k0 + dk[4]*k1 + dk[5]*k2;
      float kr2 = dk[6]*k0 + dk[7]*k1 + dk[8]*k2;
      float kd = lane < 16 ? kr0 : lane < 32 ? kr1 : lane < 48 ? kr2 : kraw;

      float p = qd * kd;
      #pragma unroll
      for (int off = 32; off; off >>= 1) p += __shfl_xor(p, off);
      s[m] = p;

      float vraw = bf2f(kvlds[m * 2048 + 1024 + h * HD + lane]);
      float v0 = __shfl(vraw, rr), v1 = __shfl(vraw, 16 + rr), v2 = __shfl(vraw, 32 + rr);
      float vr0 = dk[0]*v0 + dk[1]*v1 + dk[2]*v2;
      float vr1 = dk[3]*v0 + dk[4]*v1 + dk[5]*v2;
      float vr2 = dk[6]*v0 + dk[7]*v1 + dk[8]*v2;
      vd[m] = lane < 16 ? vr0 : lane < 32 ? vr1 : lane < 48 ? vr2 : vraw;
    }

    float mx = -INFINITY;
    #pragma unroll
    for (int m = 0; m < MN; ++m) {
      s[m] = smok[m] ? s[m] * SCALE : -INFINITY;
      mx = fmaxf(mx, s[m]);
    }
    float den = 0.f;
    #pragma unroll
    for (int m = 0; m < MN; ++m) { s[m] = expf(s[m] - mx); den += s[m]; }
    float inv = 1.0f / den;

    float od = 0.f;
    #pragma unroll
    for (int m = 0; m < MN; ++m) od += s[m] * vd[m];
    od *= inv;

    float y0 = __shfl(od, rr), y1 = __shfl(od, 16 + rr), y2 = __shfl(od, 32 + rr);
    float t0 = dq[0]*y0 + dq[3]*y1 + dq[6]*y2;
    float t1 = dq[1]*y0 + dq[4]*y1 + dq[7]*y2;
    float t2 = dq[2]*y0 + dq[5]*y1 + dq[8]*y2;
    float outd = lane < 16 ? t0 : lane < 32 ? t1 : lane < 48 ? t2 : od;

    obuf[(size_t)bn * ADIM + h * HD + lane] = __float2bfloat16(outd);
  }
}

extern "C" void kernel_launch(void* const* d_in, const int* in_sizes, int n_in,
                              void* d_out, int out_size, void* d_ws, size_t ws_size,
                              hipStream_t stream) {
  const float* x     = (const float*)d_in[0];
  const float* qkv_w = (const float*)d_in[1];
  const float* out_w = (const float*)d_in[2];
  const float* out_b = (const float*)d_in[3];
  const float* dray  = (const float*)d_in[4];
  const int* bfid  = (const int*)d_in[5];
  const int* btid  = (const int*)d_in[6];
  const int* blid  = (const int*)d_in[7];
  const int* bsid  = (const int*)d_in[8];
  const int* nfid  = (const int*)d_in[9];
  const int* ntid  = (const int*)d_in[10];
  const int* nlid  = (const int*)d_in[11];
  const int* nsid  = (const int*)d_in[12];
  const int* nmask = (const int*)d_in[13];

  char* ws = (char*)d_ws;
  short* xb    = (short*)(ws);                  // 12288*1024 bf16 = 25165824 B
  short* qwT   = (short*)(ws + 25165824);       // 3072*1024  bf16 =  6291456 B
  short* owT   = (short*)(ws + 31457280);       // 1024*1024  bf16 =  2097152 B
  float* qbuf  = (float*)(ws + 33554432);       // 1536*1024  f32  =  6291456 B
  short* kvbuf = (short*)(ws + 39845888);       // 12288*2048 bf16 = 50331648 B
  short* obuf  = (short*)(ws + 90177536);       // 1536*1024  bf16 =  3145728 B

  // zero d_out + x->bf16 + both weight transposes in one dispatch
  prep_kernel<<<16384, 256, 0, stream>>>(x, xb, (float*)d_out,
                                         qkv_w, qwT, out_w, owT);

  // Q projection: 1536 x 1024 x 1024 (64x128 tiles, 192 blocks)
  q_gemm64<<<dim3(8, 24), 256, 0, stream>>>(xb, qwT, qbuf, bfid, btid);
  // KV projection: 12288 x 2048 x 1024 (192x256, 4 fat phases, 512 blocks)
  kv_gemm192<<<dim3(8, 64), 512, 0, stream>>>(xb, qwT, kvbuf, nfid, ntid);
  // fused rotations + attention (one block per bn, LDS-staged)
  attn_kernel2<<<1536, 256, 0, stream>>>(dray, bfid, blid, bsid,
                                         nfid, ntid, nlid, nsid, nmask,
                                         qbuf, kvbuf,
                                         (__hip_bfloat16*)obuf);
  // output projection + bias + valid mask + scatter: 1536 x 1024 x 1024
  out_gemm64<<<dim3(8, 24), 256, 0, stream>>>(obuf, owT, (float*)d_out,
                                              bfid, btid, out_b);
}